// Round 8
// baseline (160.869 us; speedup 1.0000x reference)
//
#include <hip/hip_runtime.h>
#include <math.h>

#define L_NODES 16384
#define EMB 512
#define NHEAD 8
#define HDIM 64
#define DEG 16
#define NNZ_E (L_NODES * DEG)

typedef __attribute__((ext_vector_type(8))) short short8;
typedef __attribute__((ext_vector_type(4))) float f32x4;

// ---------------- fp32 -> bf16 convert (RNE) ----------------
__device__ inline short f2bs(float x) {
    union { float f; unsigned u; } c; c.f = x;
    unsigned r = (c.u + 0x7fffu + ((c.u >> 16) & 1u)) >> 16;
    return (short)r;
}

__device__ inline void cv8(const float* __restrict__ s, short* __restrict__ d, int i) {
    float4 a = reinterpret_cast<const float4*>(s)[2 * i];
    float4 b = reinterpret_cast<const float4*>(s)[2 * i + 1];
    short8 o;
    o[0] = f2bs(a.x); o[1] = f2bs(a.y); o[2] = f2bs(a.z); o[3] = f2bs(a.w);
    o[4] = f2bs(b.x); o[5] = f2bs(b.y); o[6] = f2bs(b.z); o[7] = f2bs(b.w);
    reinterpret_cast<short8*>(d)[i] = o;
}

// both weight matrices in one launch
__global__ __launch_bounds__(256) void f2bw(
    const float* __restrict__ w1, short* __restrict__ d1, int n1,
    const float* __restrict__ w2, short* __restrict__ d2, int n2) {
    const int stride = gridDim.x * blockDim.x;
    for (int i = blockIdx.x * blockDim.x + threadIdx.x; i < n1 + n2; i += stride) {
        if (i < n1) cv8(w1, d1, i); else cv8(w2, d2, i - n1);
    }
}

// bf16x8 (as short8) -> 8 floats, order-preserving (little-endian)
__device__ inline void b2f8(short8 s, float* f) {
    const unsigned* u = reinterpret_cast<const unsigned*>(&s);
#pragma unroll
    for (int j = 0; j < 4; ++j) {
        unsigned lo = u[j] << 16;
        unsigned hi = u[j] & 0xFFFF0000u;
        f[2 * j]     = __builtin_bit_cast(float, lo);
        f[2 * j + 1] = __builtin_bit_cast(float, hi);
    }
}

#define BM 128
#define BN 128
#define GBK 32
#define HBUF 4096   // shorts per half-buffer (128 rows x 32 k x 2B = 8 KB)

__device__ inline void gload16(const short* g, short* l) {
    __builtin_amdgcn_global_load_lds(
        (const __attribute__((address_space(1))) unsigned*)g,
        (__attribute__((address_space(3))) unsigned*)l, 16, 0, 0);
}

__device__ inline short8 cvt16(float4 a0, float4 a1) {
    short8 s;
    s[0] = f2bs(a0.x); s[1] = f2bs(a0.y); s[2] = f2bs(a0.z); s[3] = f2bs(a0.w);
    s[4] = f2bs(a1.x); s[5] = f2bs(a1.y); s[6] = f2bs(a1.z); s[7] = f2bs(a1.w);
    return s;
}

// ---------------- fused QKV GEMM, double-buffered + pipelined ----------------
// grid 1536: group w = blockIdx>>9 selects (input, weight slice, bias, out, scale).
// Per K-step: issue B(t+1) global_load_lds + A(t+1) reg loads FIRST, then MFMA
// on buf[cur] (hides load latency), then cvt+ds_write A(t+1) into buf[cur^1].
__global__ __launch_bounds__(256, 4) void gemm_qkv(
    const float* __restrict__ q_in, const float* __restrict__ k_in,
    const float* __restrict__ v_in, const short* __restrict__ wqkv,
    const float* __restrict__ bias_all,
    short* __restrict__ qo, short* __restrict__ ko, short* __restrict__ vo)
{
    __shared__ __align__(16) short As[2 * HBUF];
    __shared__ __align__(16) short Bs[2 * HBUF];

    const int gid   = blockIdx.x;
    const int which = gid >> 9;
    const int inner = gid & 511;

    const float* A    = which == 0 ? q_in : (which == 1 ? k_in : v_in);
    const short* B    = wqkv + which * 262144;
    const float* bias = bias_all + which * 512;
    short*       C    = which == 0 ? qo : (which == 1 ? ko : vo);
    const float scale = which == 0 ? 0.125f : 1.0f;

    const int t    = threadIdx.x;
    const int wid  = t >> 6;
    const int lane = t & 63;

    // XCD swizzle within each 512-block group
    const int wg = (inner & 7) * 64 + (inner >> 3);
    const int bx = wg & 3;
    const int by = wg >> 2;
    const int row0 = by * BM;
    const int col0 = bx * BN;

    // A staging: thread t covers row sr2 = t>>1, 16-float half khf
    const int sr2 = t >> 1;
    const int khf = (t & 1) << 4;
    const int xr  = (sr2 >> 1) & 3;
    const int p0  = (khf >> 3) ^ xr;
    const int p1  = ((khf >> 3) + 1) ^ xr;
    const float* Agp = A + (size_t)(row0 + sr2) * 512 + khf;
    short* aw0 = &As[sr2 * GBK + p0 * 8];
    short* aw1 = &As[sr2 * GBK + p1 * 8];

    // B staging (global_load_lds, source-address swizzle)
    const int sr = t >> 2;
    const int ss = (t & 3) ^ ((sr >> 1) & 3);
    const short* Bg0 = B + (size_t)(col0 + sr) * 512 + ss * 8;
    const short* Bg1 = B + (size_t)(col0 + 64 + sr) * 512 + ss * 8;
    short* Bl0 = &Bs[wid * 512];
    short* Bl1 = &Bs[2048 + wid * 512];

    const int wr = wid >> 1, wc = wid & 1;

    f32x4 acc[4][4] = {};

    // prologue: stage t=0 into half 0
    {
        gload16(Bg0, Bl0);
        gload16(Bg1, Bl1);
        float4 a0 = *reinterpret_cast<const float4*>(Agp);
        float4 a1 = *reinterpret_cast<const float4*>(Agp + 4);
        float4 a2 = *reinterpret_cast<const float4*>(Agp + 8);
        float4 a3 = *reinterpret_cast<const float4*>(Agp + 12);
        *reinterpret_cast<short8*>(aw0) = cvt16(a0, a1);
        *reinterpret_cast<short8*>(aw1) = cvt16(a2, a3);
    }
    __syncthreads();

    int cur = 0;
#pragma unroll 4
    for (int it = 0; it < 16; ++it) {
        const int off  = cur * HBUF;
        const int offn = (cur ^ 1) * HBUF;
        const bool nxt = it < 15;

        float4 a0, a1, a2, a3;
        if (nxt) {
            gload16(Bg0 + (it + 1) * 32, Bl0 + offn);
            gload16(Bg1 + (it + 1) * 32, Bl1 + offn);
            const float* ap = Agp + (it + 1) * 32;
            a0 = *reinterpret_cast<const float4*>(ap);
            a1 = *reinterpret_cast<const float4*>(ap + 4);
            a2 = *reinterpret_cast<const float4*>(ap + 8);
            a3 = *reinterpret_cast<const float4*>(ap + 12);
        }

        short8 af[4], bf[4];
#pragma unroll
        for (int i = 0; i < 4; ++i) {
            const int r  = wr * 64 + i * 16 + (lane & 15);
            const int sl = (lane >> 4) ^ ((r >> 1) & 3);
            af[i] = *reinterpret_cast<const short8*>(&As[off + r * GBK + sl * 8]);
        }
#pragma unroll
        for (int j = 0; j < 4; ++j) {
            const int r  = wc * 64 + j * 16 + (lane & 15);
            const int sl = (lane >> 4) ^ ((r >> 1) & 3);
            bf[j] = *reinterpret_cast<const short8*>(&Bs[off + r * GBK + sl * 8]);
        }
#pragma unroll
        for (int i = 0; i < 4; ++i)
#pragma unroll
            for (int j = 0; j < 4; ++j)
                acc[i][j] = __builtin_amdgcn_mfma_f32_16x16x32_bf16(
                    af[i], bf[j], acc[i][j], 0, 0, 0);

        if (nxt) {
            *reinterpret_cast<short8*>(aw0 + offn) = cvt16(a0, a1);
            *reinterpret_cast<short8*>(aw1 + offn) = cvt16(a2, a3);
        }
        __syncthreads();
        cur ^= 1;
    }

    float bv[4];
#pragma unroll
    for (int j = 0; j < 4; ++j) bv[j] = bias[col0 + wc * 64 + j * 16 + (lane & 15)];
#pragma unroll
    for (int i = 0; i < 4; ++i) {
        const int rbase = row0 + wr * 64 + i * 16 + (lane >> 4) * 4;
#pragma unroll
        for (int j = 0; j < 4; ++j) {
            const int col = col0 + wc * 64 + j * 16 + (lane & 15);
#pragma unroll
            for (int rg = 0; rg < 4; ++rg)
                C[(size_t)(rbase + rg) * 512 + col] =
                    f2bs((acc[i][j][rg] + bv[j]) * scale);
        }
    }
}

// ---------------- out-proj GEMM (bf16 A via global_load_lds, fp32 out) ----------------
__global__ __launch_bounds__(256) void gemm_out(
    const short* __restrict__ A, const short* __restrict__ B,
    const float* __restrict__ bias, float* __restrict__ C)
{
    __shared__ __align__(16) short As[BM * GBK];
    __shared__ __align__(16) short Bs[BN * GBK];

    const int t    = threadIdx.x;
    const int wid  = t >> 6;
    const int lane = t & 63;

    const int cpx = gridDim.x >> 3;
    const int bid = blockIdx.x;
    const int wg  = (bid & 7) * cpx + (bid >> 3);
    const int bx  = wg & 3;
    const int by  = wg >> 2;
    const int row0 = by * BM;
    const int col0 = bx * BN;

    const int sr = t >> 2;
    const int ss = (t & 3) ^ ((sr >> 1) & 3);
    const short* Ag0 = A + (size_t)(row0 + sr) * 512 + ss * 8;
    const short* Ag1 = A + (size_t)(row0 + 64 + sr) * 512 + ss * 8;
    const short* Bg0 = B + (size_t)(col0 + sr) * 512 + ss * 8;
    const short* Bg1 = B + (size_t)(col0 + 64 + sr) * 512 + ss * 8;
    short* Al0 = &As[wid * 512];
    short* Al1 = &As[2048 + wid * 512];
    short* Bl0 = &Bs[wid * 512];
    short* Bl1 = &Bs[2048 + wid * 512];

    const int wr = wid >> 1, wc = wid & 1;

    f32x4 acc[4][4] = {};

    for (int k0 = 0; k0 < 512; k0 += GBK) {
        gload16(Ag0 + k0, Al0);
        gload16(Ag1 + k0, Al1);
        gload16(Bg0 + k0, Bl0);
        gload16(Bg1 + k0, Bl1);
        __syncthreads();

        short8 af[4], bf[4];
#pragma unroll
        for (int i = 0; i < 4; ++i) {
            const int r  = wr * 64 + i * 16 + (lane & 15);
            const int sl = (lane >> 4) ^ ((r >> 1) & 3);
            af[i] = *reinterpret_cast<const short8*>(&As[r * GBK + sl * 8]);
        }
#pragma unroll
        for (int j = 0; j < 4; ++j) {
            const int r  = wc * 64 + j * 16 + (lane & 15);
            const int sl = (lane >> 4) ^ ((r >> 1) & 3);
            bf[j] = *reinterpret_cast<const short8*>(&Bs[r * GBK + sl * 8]);
        }
#pragma unroll
        for (int i = 0; i < 4; ++i)
#pragma unroll
            for (int j = 0; j < 4; ++j)
                acc[i][j] = __builtin_amdgcn_mfma_f32_16x16x32_bf16(
                    af[i], bf[j], acc[i][j], 0, 0, 0);
        __syncthreads();
    }

    float bv[4];
#pragma unroll
    for (int j = 0; j < 4; ++j) bv[j] = bias[col0 + wc * 64 + j * 16 + (lane & 15)];
#pragma unroll
    for (int i = 0; i < 4; ++i) {
        const int rbase = row0 + wr * 64 + i * 16 + (lane >> 4) * 4;
#pragma unroll
        for (int j = 0; j < 4; ++j) {
            const int col = col0 + wc * 64 + j * 16 + (lane & 15);
#pragma unroll
            for (int rg = 0; rg < 4; ++rg)
                C[(size_t)(rbase + rg) * 512 + col] = acc[i][j][rg] + bv[j];
        }
    }
}

// ---------------- edge softmax/aggregate, v4: 2 nodes/block ----------------
__device__ inline float edge_core(const float* qf, short8 k0, short8 k1,
                                  short8 v0, short8 v1, int lane) {
    float kf0[8], kf1[8];
    b2f8(k0, kf0); b2f8(k1, kf1);
    float p0 = 0.f, p1 = 0.f;
#pragma unroll
    for (int j = 0; j < 8; ++j) { p0 += qf[j] * kf0[j]; p1 += qf[j] * kf1[j]; }

    const bool b0 = (lane & 1) != 0;
    float x = b0 ? p0 : p1;
    float r = __shfl_xor(x, 1, 64);
    float s = (b0 ? p1 : p0) + r;
    s += __shfl_xor(s, 2, 64);
    s += __shfl_xor(s, 4, 64);

    float m = s;
    m = fmaxf(m, __shfl_xor(m, 1, 64));
    m = fmaxf(m, __shfl_xor(m, 8, 64));
    m = fmaxf(m, __shfl_xor(m, 16, 64));
    m = fmaxf(m, __shfl_xor(m, 32, 64));
    float w = expf(s - m);
    float den = w;
    den += __shfl_xor(den, 1, 64);
    den += __shfl_xor(den, 8, 64);
    den += __shfl_xor(den, 16, 64);
    den += __shfl_xor(den, 32, 64);
    w *= (1.0f / den);

    const int srcb = lane & 56;
    const float w0 = __shfl(w, srcb, 64);
    const float w1 = __shfl(w, srcb | 1, 64);

    float vf0[8], vf1[8], of[8];
    b2f8(v0, vf0); b2f8(v1, vf1);
#pragma unroll
    for (int j = 0; j < 8; ++j) of[j] = w0 * vf0[j] + w1 * vf1[j];

    const bool b3 = (lane & 8) != 0;
    float o4[4];
#pragma unroll
    for (int j = 0; j < 4; ++j) {
        float send = b3 ? of[j] : of[4 + j];
        float recv = __shfl_xor(send, 8, 64);
        o4[j] = (b3 ? of[4 + j] : of[j]) + recv;
    }
    const bool b4 = (lane & 16) != 0;
    float z0 = __shfl_xor(b4 ? o4[0] : o4[2], 16, 64);
    float z1 = __shfl_xor(b4 ? o4[1] : o4[3], 16, 64);
    float t0 = (b4 ? o4[2] : o4[0]) + z0;
    float t1 = (b4 ? o4[3] : o4[1]) + z1;
    const bool b5 = (lane & 32) != 0;
    float zz = __shfl_xor(b5 ? t0 : t1, 32, 64);
    return (b5 ? t1 : t0) + zz;
}

__global__ __launch_bounds__(512) void edge_attn4(
    const short* __restrict__ qm, const short* __restrict__ km,
    const short* __restrict__ vm, const int* __restrict__ colidx,
    short* __restrict__ outb)
{
    const int i0   = blockIdx.x << 1;
    const int h    = threadIdx.x >> 6;
    const int lane = threadIdx.x & 63;
    const int c    = lane & 7;
    const int g    = lane >> 3;

    int creg = 0;
    if (lane < 2 * DEG) creg = colidx[i0 * DEG + lane];
    const int ca0 = __shfl(creg, g, 64);
    const int ca1 = __shfl(creg, g + 8, 64);
    const int cb0 = __shfl(creg, 16 + g, 64);
    const int cb1 = __shfl(creg, 16 + g + 8, 64);

    const size_t dof = (size_t)h * HDIM + 8 * c;
    short8 qA  = *reinterpret_cast<const short8*>(&qm[(size_t)i0 * EMB + dof]);
    short8 qB  = *reinterpret_cast<const short8*>(&qm[(size_t)(i0 + 1) * EMB + dof]);
    short8 kA0 = *reinterpret_cast<const short8*>(&km[(size_t)ca0 * EMB + dof]);
    short8 kA1 = *reinterpret_cast<const short8*>(&km[(size_t)ca1 * EMB + dof]);
    short8 kB0 = *reinterpret_cast<const short8*>(&km[(size_t)cb0 * EMB + dof]);
    short8 kB1 = *reinterpret_cast<const short8*>(&km[(size_t)cb1 * EMB + dof]);
    short8 vA0 = *reinterpret_cast<const short8*>(&vm[(size_t)ca0 * EMB + dof]);
    short8 vA1 = *reinterpret_cast<const short8*>(&vm[(size_t)ca1 * EMB + dof]);
    short8 vB0 = *reinterpret_cast<const short8*>(&vm[(size_t)cb0 * EMB + dof]);
    short8 vB1 = *reinterpret_cast<const short8*>(&vm[(size_t)cb1 * EMB + dof]);

    float qfA[8], qfB[8];
    b2f8(qA, qfA); b2f8(qB, qfB);

    const float oA = edge_core(qfA, kA0, kA1, vA0, vA1, lane);
    const float oB = edge_core(qfB, kB0, kB1, vB0, vB1, lane);

    const int d = 8 * c + ((lane & 8) ? 4 : 0) + ((lane & 16) ? 2 : 0)
                        + ((lane & 32) ? 1 : 0);
    outb[(size_t)i0 * EMB + h * HDIM + d]       = f2bs(oA);
    outb[(size_t)(i0 + 1) * EMB + h * HDIM + d] = f2bs(oB);
}

// ---------------- fp32 fallback path ----------------
#define TILE 64
#define BKK 16
#define PAD_LD 68

__global__ __launch_bounds__(256) void gemm_bt(
    const float* __restrict__ A, const float* __restrict__ W,
    const float* __restrict__ bias, float* __restrict__ C,
    int M, int K, int N, float scale)
{
    __shared__ float Asm[BKK][PAD_LD];
    __shared__ float Bsm[BKK][PAD_LD];
    const int t  = threadIdx.x;
    const int tx = t & 15;
    const int ty = t >> 4;
    const int row0 = blockIdx.y * TILE;
    const int col0 = blockIdx.x * TILE;
    const int lr = t >> 2;
    const int lk = (t & 3) << 2;
    const float* Aptr = A + (size_t)(row0 + lr) * K + lk;
    const float* Wptr = W + (size_t)(col0 + lr) * K + lk;
    float acc[4][4] = {};
    for (int k0 = 0; k0 < K; k0 += BKK) {
        float4 a4 = *reinterpret_cast<const float4*>(Aptr + k0);
        float4 b4 = *reinterpret_cast<const float4*>(Wptr + k0);
        Asm[lk + 0][lr] = a4.x; Asm[lk + 1][lr] = a4.y;
        Asm[lk + 2][lr] = a4.z; Asm[lk + 3][lr] = a4.w;
        Bsm[lk + 0][lr] = b4.x; Bsm[lk + 1][lr] = b4.y;
        Bsm[lk + 2][lr] = b4.z; Bsm[lk + 3][lr] = b4.w;
        __syncthreads();
#pragma unroll
        for (int kk = 0; kk < BKK; ++kk) {
            float a[4], b[4];
#pragma unroll
            for (int i2 = 0; i2 < 4; ++i2) a[i2] = Asm[kk][ty * 4 + i2];
#pragma unroll
            for (int j2 = 0; j2 < 4; ++j2) b[j2] = Bsm[kk][tx * 4 + j2];
#pragma unroll
            for (int i2 = 0; i2 < 4; ++i2)
#pragma unroll
                for (int j2 = 0; j2 < 4; ++j2)
                    acc[i2][j2] += a[i2] * b[j2];
        }
        __syncthreads();
    }
#pragma unroll
    for (int i2 = 0; i2 < 4; ++i2) {
        const int r = row0 + ty * 4 + i2;
        float4 o;
        o.x = (acc[i2][0] + bias[col0 + tx * 4 + 0]) * scale;
        o.y = (acc[i2][1] + bias[col0 + tx * 4 + 1]) * scale;
        o.z = (acc[i2][2] + bias[col0 + tx * 4 + 2]) * scale;
        o.w = (acc[i2][3] + bias[col0 + tx * 4 + 3]) * scale;
        *reinterpret_cast<float4*>(&C[(size_t)r * N + col0 + tx * 4]) = o;
    }
}

__global__ __launch_bounds__(512) void edge_attn(
    const float* q, const float* __restrict__ kmat, const float* __restrict__ vmat,
    const int* __restrict__ colidx, float* out)
{
    const int i    = blockIdx.x;
    const int h    = threadIdx.x >> 6;
    const int lane = threadIdx.x & 63;
    const size_t base = (size_t)i * EMB + h * HDIM + lane;

    const float qd = q[base];
    int creg = 0;
    if (lane < DEG) creg = colidx[i * DEG + lane];

    float kr[DEG], vr[DEG];
#pragma unroll
    for (int e = 0; e < DEG; ++e) {
        const int ce = __shfl(creg, e, 64);
        const size_t cb = (size_t)ce * EMB + h * HDIM + lane;
        kr[e] = kmat[cb];
        vr[e] = vmat[cb];
    }
    float s[DEG];
#pragma unroll
    for (int e = 0; e < DEG; ++e) {
        float p = qd * kr[e];
#pragma unroll
        for (int off = 32; off; off >>= 1) p += __shfl_xor(p, off, 64);
        s[e] = p;
    }
    float m = s[0];
#pragma unroll
    for (int e = 1; e < DEG; ++e) m = fmaxf(m, s[e]);
    float denom = 0.f;
#pragma unroll
    for (int e = 0; e < DEG; ++e) { s[e] = expf(s[e] - m); denom += s[e]; }
    const float inv = 1.f / denom;
    float o = 0.f;
#pragma unroll
    for (int e = 0; e < DEG; ++e) o += s[e] * vr[e];
    out[base] = o * inv;
}

extern "C" void kernel_launch(void* const* d_in, const int* in_sizes, int n_in,
                              void* d_out, int out_size, void* d_ws, size_t ws_size,
                              hipStream_t stream) {
    const float* query   = (const float*)d_in[0];
    const float* key_    = (const float*)d_in[1];
    const float* value   = (const float*)d_in[2];
    const int*   indices = (const int*)  d_in[3];
    const float* ipw     = (const float*)d_in[4];
    const float* ipb     = (const float*)d_in[5];
    const float* opw     = (const float*)d_in[6];
    const float* opb     = (const float*)d_in[7];
    float* out = (float*)d_out;

    const size_t NEED = 70000000;  // shorts: wqkv+wo+qo+ko+vo+ab = 69.2 MB

    if (ws_size >= NEED) {
        short* wqkv = (short*)d_ws;          // 786432
        short* wo   = wqkv + 786432;         // 262144
        short* qo   = wo + 262144;           // 8388608 each
        short* ko   = qo + 8388608;
        short* vo   = ko + 8388608;
        short* ab   = vo + 8388608;          // attn out bf16

        f2bw<<<512, 256, 0, stream>>>(ipw, wqkv, 98304, opw, wo, 32768);
        gemm_qkv<<<1536, 256, 0, stream>>>(query, key_, value, wqkv, ipb,
                                           qo, ko, vo);
        edge_attn4<<<L_NODES / 2, 512, 0, stream>>>(qo, ko, vo,
                                                    indices + NNZ_E, ab);
        gemm_out<<<512, 256, 0, stream>>>(ab, wo, opb, out);
    } else {
        float* qbuf = (float*)d_ws;
        float* kbuf = qbuf + (size_t)L_NODES * EMB;
        float* vbuf = kbuf + (size_t)L_NODES * EMB;
        const dim3 gblk(EMB / TILE, L_NODES / TILE);
        const float scaling = 0.125f;
        gemm_bt<<<gblk, 256, 0, stream>>>(query, ipw,                 ipb,         qbuf,
                                          L_NODES, EMB, EMB, scaling);
        gemm_bt<<<gblk, 256, 0, stream>>>(key_,  ipw + 1 * EMB * EMB, ipb + EMB,   kbuf,
                                          L_NODES, EMB, EMB, 1.f);
        gemm_bt<<<gblk, 256, 0, stream>>>(value, ipw + 2 * EMB * EMB, ipb + 2*EMB, vbuf,
                                          L_NODES, EMB, EMB, 1.f);
        edge_attn<<<L_NODES, 512, 0, stream>>>(qbuf, kbuf, vbuf, indices + NNZ_E, qbuf);
        gemm_bt<<<gblk, 256, 0, stream>>>(qbuf, opw, opb, out, L_NODES, EMB, EMB, 1.f);
    }
}

// Round 9
// 146.084 us; speedup vs baseline: 1.1012x; 1.1012x over previous
//
#include <hip/hip_runtime.h>
#include <math.h>

#define L_NODES 16384
#define EMB 512
#define NHEAD 8
#define HDIM 64
#define DEG 16
#define NNZ_E (L_NODES * DEG)

typedef __attribute__((ext_vector_type(8))) short short8;
typedef __attribute__((ext_vector_type(4))) float f32x4;

// ---------------- fp32 -> bf16 convert (RNE) ----------------
__device__ inline short f2bs(float x) {
    union { float f; unsigned u; } c; c.f = x;
    unsigned r = (c.u + 0x7fffu + ((c.u >> 16) & 1u)) >> 16;
    return (short)r;
}

__device__ inline void cv8(const float* __restrict__ s, short* __restrict__ d, int i) {
    float4 a = reinterpret_cast<const float4*>(s)[2 * i];
    float4 b = reinterpret_cast<const float4*>(s)[2 * i + 1];
    short8 o;
    o[0] = f2bs(a.x); o[1] = f2bs(a.y); o[2] = f2bs(a.z); o[3] = f2bs(a.w);
    o[4] = f2bs(b.x); o[5] = f2bs(b.y); o[6] = f2bs(b.z); o[7] = f2bs(b.w);
    reinterpret_cast<short8*>(d)[i] = o;
}

// both weight matrices in one launch
__global__ __launch_bounds__(256) void f2bw(
    const float* __restrict__ w1, short* __restrict__ d1, int n1,
    const float* __restrict__ w2, short* __restrict__ d2, int n2) {
    const int stride = gridDim.x * blockDim.x;
    for (int i = blockIdx.x * blockDim.x + threadIdx.x; i < n1 + n2; i += stride) {
        if (i < n1) cv8(w1, d1, i); else cv8(w2, d2, i - n1);
    }
}

// bf16x8 (as short8) -> 8 floats, order-preserving (little-endian)
__device__ inline void b2f8(short8 s, float* f) {
    const unsigned* u = reinterpret_cast<const unsigned*>(&s);
#pragma unroll
    for (int j = 0; j < 4; ++j) {
        unsigned lo = u[j] << 16;
        unsigned hi = u[j] & 0xFFFF0000u;
        f[2 * j]     = __builtin_bit_cast(float, lo);
        f[2 * j + 1] = __builtin_bit_cast(float, hi);
    }
}

#define BM 128
#define BN 128
#define GBK 32
#define HBUF 4096   // shorts per half-buffer (128 rows x 32 k x 2B = 8 KB)

__device__ inline void gload16(const short* g, short* l) {
    __builtin_amdgcn_global_load_lds(
        (const __attribute__((address_space(1))) unsigned*)g,
        (__attribute__((address_space(3))) unsigned*)l, 16, 0, 0);
}

__device__ inline short8 cvt16(float4 a0, float4 a1) {
    short8 s;
    s[0] = f2bs(a0.x); s[1] = f2bs(a0.y); s[2] = f2bs(a0.z); s[3] = f2bs(a0.w);
    s[4] = f2bs(a1.x); s[5] = f2bs(a1.y); s[6] = f2bs(a1.z); s[7] = f2bs(a1.w);
    return s;
}

// ---------------- fused QKV GEMM, double-buffered + pipelined ----------------
// grid 1536: group w = blockIdx>>9 selects (input, weight slice, bias, out, scale).
// Per K-step: issue B(t+1) global_load_lds + A(t+1) reg loads FIRST, then MFMA
// on buf[cur] (hides load latency), then cvt+ds_write A(t+1) into buf[cur^1].
// NO occupancy clamp: round-8's (256,4) forced VGPR=64 -> scratch spills
// (WRITE_SIZE +21 MB, MfmaUtil 10%). Let the allocator take ~120-160.
__global__ __launch_bounds__(256) void gemm_qkv(
    const float* __restrict__ q_in, const float* __restrict__ k_in,
    const float* __restrict__ v_in, const short* __restrict__ wqkv,
    const float* __restrict__ bias_all,
    short* __restrict__ qo, short* __restrict__ ko, short* __restrict__ vo)
{
    __shared__ __align__(16) short As[2 * HBUF];
    __shared__ __align__(16) short Bs[2 * HBUF];

    const int gid   = blockIdx.x;
    const int which = gid >> 9;
    const int inner = gid & 511;

    const float* A    = which == 0 ? q_in : (which == 1 ? k_in : v_in);
    const short* B    = wqkv + which * 262144;
    const float* bias = bias_all + which * 512;
    short*       C    = which == 0 ? qo : (which == 1 ? ko : vo);
    const float scale = which == 0 ? 0.125f : 1.0f;

    const int t    = threadIdx.x;
    const int wid  = t >> 6;
    const int lane = t & 63;

    // XCD swizzle within each 512-block group
    const int wg = (inner & 7) * 64 + (inner >> 3);
    const int bx = wg & 3;
    const int by = wg >> 2;
    const int row0 = by * BM;
    const int col0 = bx * BN;

    // A staging: thread t covers row sr2 = t>>1, 16-float half khf
    const int sr2 = t >> 1;
    const int khf = (t & 1) << 4;
    const int xr  = (sr2 >> 1) & 3;
    const int p0  = (khf >> 3) ^ xr;
    const int p1  = ((khf >> 3) + 1) ^ xr;
    const float* Agp = A + (size_t)(row0 + sr2) * 512 + khf;
    short* aw0 = &As[sr2 * GBK + p0 * 8];
    short* aw1 = &As[sr2 * GBK + p1 * 8];

    // B staging (global_load_lds, source-address swizzle)
    const int sr = t >> 2;
    const int ss = (t & 3) ^ ((sr >> 1) & 3);
    const short* Bg0 = B + (size_t)(col0 + sr) * 512 + ss * 8;
    const short* Bg1 = B + (size_t)(col0 + 64 + sr) * 512 + ss * 8;
    short* Bl0 = &Bs[wid * 512];
    short* Bl1 = &Bs[2048 + wid * 512];

    const int wr = wid >> 1, wc = wid & 1;

    f32x4 acc[4][4] = {};

    // prologue: stage t=0 into half 0
    {
        gload16(Bg0, Bl0);
        gload16(Bg1, Bl1);
        float4 a0 = *reinterpret_cast<const float4*>(Agp);
        float4 a1 = *reinterpret_cast<const float4*>(Agp + 4);
        float4 a2 = *reinterpret_cast<const float4*>(Agp + 8);
        float4 a3 = *reinterpret_cast<const float4*>(Agp + 12);
        *reinterpret_cast<short8*>(aw0) = cvt16(a0, a1);
        *reinterpret_cast<short8*>(aw1) = cvt16(a2, a3);
    }
    __syncthreads();

    int cur = 0;
#pragma unroll 2
    for (int it = 0; it < 16; ++it) {
        const int off  = cur * HBUF;
        const int offn = (cur ^ 1) * HBUF;
        const bool nxt = it < 15;

        float4 a0, a1, a2, a3;
        if (nxt) {
            gload16(Bg0 + (it + 1) * 32, Bl0 + offn);
            gload16(Bg1 + (it + 1) * 32, Bl1 + offn);
            const float* ap = Agp + (it + 1) * 32;
            a0 = *reinterpret_cast<const float4*>(ap);
            a1 = *reinterpret_cast<const float4*>(ap + 4);
            a2 = *reinterpret_cast<const float4*>(ap + 8);
            a3 = *reinterpret_cast<const float4*>(ap + 12);
        }

        short8 af[4], bf[4];
#pragma unroll
        for (int i = 0; i < 4; ++i) {
            const int r  = wr * 64 + i * 16 + (lane & 15);
            const int sl = (lane >> 4) ^ ((r >> 1) & 3);
            af[i] = *reinterpret_cast<const short8*>(&As[off + r * GBK + sl * 8]);
        }
#pragma unroll
        for (int j = 0; j < 4; ++j) {
            const int r  = wc * 64 + j * 16 + (lane & 15);
            const int sl = (lane >> 4) ^ ((r >> 1) & 3);
            bf[j] = *reinterpret_cast<const short8*>(&Bs[off + r * GBK + sl * 8]);
        }
#pragma unroll
        for (int i = 0; i < 4; ++i)
#pragma unroll
            for (int j = 0; j < 4; ++j)
                acc[i][j] = __builtin_amdgcn_mfma_f32_16x16x32_bf16(
                    af[i], bf[j], acc[i][j], 0, 0, 0);

        if (nxt) {
            *reinterpret_cast<short8*>(aw0 + offn) = cvt16(a0, a1);
            *reinterpret_cast<short8*>(aw1 + offn) = cvt16(a2, a3);
        }
        __syncthreads();
        cur ^= 1;
    }

    float bv[4];
#pragma unroll
    for (int j = 0; j < 4; ++j) bv[j] = bias[col0 + wc * 64 + j * 16 + (lane & 15)];
#pragma unroll
    for (int i = 0; i < 4; ++i) {
        const int rbase = row0 + wr * 64 + i * 16 + (lane >> 4) * 4;
#pragma unroll
        for (int j = 0; j < 4; ++j) {
            const int col = col0 + wc * 64 + j * 16 + (lane & 15);
#pragma unroll
            for (int rg = 0; rg < 4; ++rg)
                C[(size_t)(rbase + rg) * 512 + col] =
                    f2bs((acc[i][j][rg] + bv[j]) * scale);
        }
    }
}

// ---------------- out-proj GEMM (bf16 A via global_load_lds, fp32 out) ----------------
__global__ __launch_bounds__(256) void gemm_out(
    const short* __restrict__ A, const short* __restrict__ B,
    const float* __restrict__ bias, float* __restrict__ C)
{
    __shared__ __align__(16) short As[BM * GBK];
    __shared__ __align__(16) short Bs[BN * GBK];

    const int t    = threadIdx.x;
    const int wid  = t >> 6;
    const int lane = t & 63;

    const int cpx = gridDim.x >> 3;
    const int bid = blockIdx.x;
    const int wg  = (bid & 7) * cpx + (bid >> 3);
    const int bx  = wg & 3;
    const int by  = wg >> 2;
    const int row0 = by * BM;
    const int col0 = bx * BN;

    const int sr = t >> 2;
    const int ss = (t & 3) ^ ((sr >> 1) & 3);
    const short* Ag0 = A + (size_t)(row0 + sr) * 512 + ss * 8;
    const short* Ag1 = A + (size_t)(row0 + 64 + sr) * 512 + ss * 8;
    const short* Bg0 = B + (size_t)(col0 + sr) * 512 + ss * 8;
    const short* Bg1 = B + (size_t)(col0 + 64 + sr) * 512 + ss * 8;
    short* Al0 = &As[wid * 512];
    short* Al1 = &As[2048 + wid * 512];
    short* Bl0 = &Bs[wid * 512];
    short* Bl1 = &Bs[2048 + wid * 512];

    const int wr = wid >> 1, wc = wid & 1;

    f32x4 acc[4][4] = {};

    for (int k0 = 0; k0 < 512; k0 += GBK) {
        gload16(Ag0 + k0, Al0);
        gload16(Ag1 + k0, Al1);
        gload16(Bg0 + k0, Bl0);
        gload16(Bg1 + k0, Bl1);
        __syncthreads();

        short8 af[4], bf[4];
#pragma unroll
        for (int i = 0; i < 4; ++i) {
            const int r  = wr * 64 + i * 16 + (lane & 15);
            const int sl = (lane >> 4) ^ ((r >> 1) & 3);
            af[i] = *reinterpret_cast<const short8*>(&As[r * GBK + sl * 8]);
        }
#pragma unroll
        for (int j = 0; j < 4; ++j) {
            const int r  = wc * 64 + j * 16 + (lane & 15);
            const int sl = (lane >> 4) ^ ((r >> 1) & 3);
            bf[j] = *reinterpret_cast<const short8*>(&Bs[r * GBK + sl * 8]);
        }
#pragma unroll
        for (int i = 0; i < 4; ++i)
#pragma unroll
            for (int j = 0; j < 4; ++j)
                acc[i][j] = __builtin_amdgcn_mfma_f32_16x16x32_bf16(
                    af[i], bf[j], acc[i][j], 0, 0, 0);
        __syncthreads();
    }

    float bv[4];
#pragma unroll
    for (int j = 0; j < 4; ++j) bv[j] = bias[col0 + wc * 64 + j * 16 + (lane & 15)];
#pragma unroll
    for (int i = 0; i < 4; ++i) {
        const int rbase = row0 + wr * 64 + i * 16 + (lane >> 4) * 4;
#pragma unroll
        for (int j = 0; j < 4; ++j) {
            const int col = col0 + wc * 64 + j * 16 + (lane & 15);
#pragma unroll
            for (int rg = 0; rg < 4; ++rg)
                C[(size_t)(rbase + rg) * 512 + col] = acc[i][j][rg] + bv[j];
        }
    }
}

// ---------------- edge softmax/aggregate, v4: 2 nodes/block ----------------
__device__ inline float edge_core(const float* qf, short8 k0, short8 k1,
                                  short8 v0, short8 v1, int lane) {
    float kf0[8], kf1[8];
    b2f8(k0, kf0); b2f8(k1, kf1);
    float p0 = 0.f, p1 = 0.f;
#pragma unroll
    for (int j = 0; j < 8; ++j) { p0 += qf[j] * kf0[j]; p1 += qf[j] * kf1[j]; }

    const bool b0 = (lane & 1) != 0;
    float x = b0 ? p0 : p1;
    float r = __shfl_xor(x, 1, 64);
    float s = (b0 ? p1 : p0) + r;
    s += __shfl_xor(s, 2, 64);
    s += __shfl_xor(s, 4, 64);

    float m = s;
    m = fmaxf(m, __shfl_xor(m, 1, 64));
    m = fmaxf(m, __shfl_xor(m, 8, 64));
    m = fmaxf(m, __shfl_xor(m, 16, 64));
    m = fmaxf(m, __shfl_xor(m, 32, 64));
    float w = expf(s - m);
    float den = w;
    den += __shfl_xor(den, 1, 64);
    den += __shfl_xor(den, 8, 64);
    den += __shfl_xor(den, 16, 64);
    den += __shfl_xor(den, 32, 64);
    w *= (1.0f / den);

    const int srcb = lane & 56;
    const float w0 = __shfl(w, srcb, 64);
    const float w1 = __shfl(w, srcb | 1, 64);

    float vf0[8], vf1[8], of[8];
    b2f8(v0, vf0); b2f8(v1, vf1);
#pragma unroll
    for (int j = 0; j < 8; ++j) of[j] = w0 * vf0[j] + w1 * vf1[j];

    const bool b3 = (lane & 8) != 0;
    float o4[4];
#pragma unroll
    for (int j = 0; j < 4; ++j) {
        float send = b3 ? of[j] : of[4 + j];
        float recv = __shfl_xor(send, 8, 64);
        o4[j] = (b3 ? of[4 + j] : of[j]) + recv;
    }
    const bool b4 = (lane & 16) != 0;
    float z0 = __shfl_xor(b4 ? o4[0] : o4[2], 16, 64);
    float z1 = __shfl_xor(b4 ? o4[1] : o4[3], 16, 64);
    float t0 = (b4 ? o4[2] : o4[0]) + z0;
    float t1 = (b4 ? o4[3] : o4[1]) + z1;
    const bool b5 = (lane & 32) != 0;
    float zz = __shfl_xor(b5 ? t0 : t1, 32, 64);
    return (b5 ? t1 : t0) + zz;
}

__global__ __launch_bounds__(512) void edge_attn4(
    const short* __restrict__ qm, const short* __restrict__ km,
    const short* __restrict__ vm, const int* __restrict__ colidx,
    short* __restrict__ outb)
{
    const int i0   = blockIdx.x << 1;
    const int h    = threadIdx.x >> 6;
    const int lane = threadIdx.x & 63;
    const int c    = lane & 7;
    const int g    = lane >> 3;

    int creg = 0;
    if (lane < 2 * DEG) creg = colidx[i0 * DEG + lane];
    const int ca0 = __shfl(creg, g, 64);
    const int ca1 = __shfl(creg, g + 8, 64);
    const int cb0 = __shfl(creg, 16 + g, 64);
    const int cb1 = __shfl(creg, 16 + g + 8, 64);

    const size_t dof = (size_t)h * HDIM + 8 * c;
    short8 qA  = *reinterpret_cast<const short8*>(&qm[(size_t)i0 * EMB + dof]);
    short8 qB  = *reinterpret_cast<const short8*>(&qm[(size_t)(i0 + 1) * EMB + dof]);
    short8 kA0 = *reinterpret_cast<const short8*>(&km[(size_t)ca0 * EMB + dof]);
    short8 kA1 = *reinterpret_cast<const short8*>(&km[(size_t)ca1 * EMB + dof]);
    short8 kB0 = *reinterpret_cast<const short8*>(&km[(size_t)cb0 * EMB + dof]);
    short8 kB1 = *reinterpret_cast<const short8*>(&km[(size_t)cb1 * EMB + dof]);
    short8 vA0 = *reinterpret_cast<const short8*>(&vm[(size_t)ca0 * EMB + dof]);
    short8 vA1 = *reinterpret_cast<const short8*>(&vm[(size_t)ca1 * EMB + dof]);
    short8 vB0 = *reinterpret_cast<const short8*>(&vm[(size_t)cb0 * EMB + dof]);
    short8 vB1 = *reinterpret_cast<const short8*>(&vm[(size_t)cb1 * EMB + dof]);

    float qfA[8], qfB[8];
    b2f8(qA, qfA); b2f8(qB, qfB);

    const float oA = edge_core(qfA, kA0, kA1, vA0, vA1, lane);
    const float oB = edge_core(qfB, kB0, kB1, vB0, vB1, lane);

    const int d = 8 * c + ((lane & 8) ? 4 : 0) + ((lane & 16) ? 2 : 0)
                        + ((lane & 32) ? 1 : 0);
    outb[(size_t)i0 * EMB + h * HDIM + d]       = f2bs(oA);
    outb[(size_t)(i0 + 1) * EMB + h * HDIM + d] = f2bs(oB);
}

// ---------------- fp32 fallback path ----------------
#define TILE 64
#define BKK 16
#define PAD_LD 68

__global__ __launch_bounds__(256) void gemm_bt(
    const float* __restrict__ A, const float* __restrict__ W,
    const float* __restrict__ bias, float* __restrict__ C,
    int M, int K, int N, float scale)
{
    __shared__ float Asm[BKK][PAD_LD];
    __shared__ float Bsm[BKK][PAD_LD];
    const int t  = threadIdx.x;
    const int tx = t & 15;
    const int ty = t >> 4;
    const int row0 = blockIdx.y * TILE;
    const int col0 = blockIdx.x * TILE;
    const int lr = t >> 2;
    const int lk = (t & 3) << 2;
    const float* Aptr = A + (size_t)(row0 + lr) * K + lk;
    const float* Wptr = W + (size_t)(col0 + lr) * K + lk;
    float acc[4][4] = {};
    for (int k0 = 0; k0 < K; k0 += BKK) {
        float4 a4 = *reinterpret_cast<const float4*>(Aptr + k0);
        float4 b4 = *reinterpret_cast<const float4*>(Wptr + k0);
        Asm[lk + 0][lr] = a4.x; Asm[lk + 1][lr] = a4.y;
        Asm[lk + 2][lr] = a4.z; Asm[lk + 3][lr] = a4.w;
        Bsm[lk + 0][lr] = b4.x; Bsm[lk + 1][lr] = b4.y;
        Bsm[lk + 2][lr] = b4.z; Bsm[lk + 3][lr] = b4.w;
        __syncthreads();
#pragma unroll
        for (int kk = 0; kk < BKK; ++kk) {
            float a[4], b[4];
#pragma unroll
            for (int i2 = 0; i2 < 4; ++i2) a[i2] = Asm[kk][ty * 4 + i2];
#pragma unroll
            for (int j2 = 0; j2 < 4; ++j2) b[j2] = Bsm[kk][tx * 4 + j2];
#pragma unroll
            for (int i2 = 0; i2 < 4; ++i2)
#pragma unroll
                for (int j2 = 0; j2 < 4; ++j2)
                    acc[i2][j2] += a[i2] * b[j2];
        }
        __syncthreads();
    }
#pragma unroll
    for (int i2 = 0; i2 < 4; ++i2) {
        const int r = row0 + ty * 4 + i2;
        float4 o;
        o.x = (acc[i2][0] + bias[col0 + tx * 4 + 0]) * scale;
        o.y = (acc[i2][1] + bias[col0 + tx * 4 + 1]) * scale;
        o.z = (acc[i2][2] + bias[col0 + tx * 4 + 2]) * scale;
        o.w = (acc[i2][3] + bias[col0 + tx * 4 + 3]) * scale;
        *reinterpret_cast<float4*>(&C[(size_t)r * N + col0 + tx * 4]) = o;
    }
}

__global__ __launch_bounds__(512) void edge_attn(
    const float* q, const float* __restrict__ kmat, const float* __restrict__ vmat,
    const int* __restrict__ colidx, float* out)
{
    const int i    = blockIdx.x;
    const int h    = threadIdx.x >> 6;
    const int lane = threadIdx.x & 63;
    const size_t base = (size_t)i * EMB + h * HDIM + lane;

    const float qd = q[base];
    int creg = 0;
    if (lane < DEG) creg = colidx[i * DEG + lane];

    float kr[DEG], vr[DEG];
#pragma unroll
    for (int e = 0; e < DEG; ++e) {
        const int ce = __shfl(creg, e, 64);
        const size_t cb = (size_t)ce * EMB + h * HDIM + lane;
        kr[e] = kmat[cb];
        vr[e] = vmat[cb];
    }
    float s[DEG];
#pragma unroll
    for (int e = 0; e < DEG; ++e) {
        float p = qd * kr[e];
#pragma unroll
        for (int off = 32; off; off >>= 1) p += __shfl_xor(p, off, 64);
        s[e] = p;
    }
    float m = s[0];
#pragma unroll
    for (int e = 1; e < DEG; ++e) m = fmaxf(m, s[e]);
    float denom = 0.f;
#pragma unroll
    for (int e = 0; e < DEG; ++e) { s[e] = expf(s[e] - m); denom += s[e]; }
    const float inv = 1.f / denom;
    float o = 0.f;
#pragma unroll
    for (int e = 0; e < DEG; ++e) o += s[e] * vr[e];
    out[base] = o * inv;
}

extern "C" void kernel_launch(void* const* d_in, const int* in_sizes, int n_in,
                              void* d_out, int out_size, void* d_ws, size_t ws_size,
                              hipStream_t stream) {
    const float* query   = (const float*)d_in[0];
    const float* key_    = (const float*)d_in[1];
    const float* value   = (const float*)d_in[2];
    const int*   indices = (const int*)  d_in[3];
    const float* ipw     = (const float*)d_in[4];
    const float* ipb     = (const float*)d_in[5];
    const float* opw     = (const float*)d_in[6];
    const float* opb     = (const float*)d_in[7];
    float* out = (float*)d_out;

    const size_t NEED = 70000000;  // shorts: wqkv+wo+qo+ko+vo+ab = 69.2 MB

    if (ws_size >= NEED) {
        short* wqkv = (short*)d_ws;          // 786432
        short* wo   = wqkv + 786432;         // 262144
        short* qo   = wo + 262144;           // 8388608 each
        short* ko   = qo + 8388608;
        short* vo   = ko + 8388608;
        short* ab   = vo + 8388608;          // attn out bf16

        f2bw<<<512, 256, 0, stream>>>(ipw, wqkv, 98304, opw, wo, 32768);
        gemm_qkv<<<1536, 256, 0, stream>>>(query, key_, value, wqkv, ipb,
                                           qo, ko, vo);
        edge_attn4<<<L_NODES / 2, 512, 0, stream>>>(qo, ko, vo,
                                                    indices + NNZ_E, ab);
        gemm_out<<<512, 256, 0, stream>>>(ab, wo, opb, out);
    } else {
        float* qbuf = (float*)d_ws;
        float* kbuf = qbuf + (size_t)L_NODES * EMB;
        float* vbuf = kbuf + (size_t)L_NODES * EMB;
        const dim3 gblk(EMB / TILE, L_NODES / TILE);
        const float scaling = 0.125f;
        gemm_bt<<<gblk, 256, 0, stream>>>(query, ipw,                 ipb,         qbuf,
                                          L_NODES, EMB, EMB, scaling);
        gemm_bt<<<gblk, 256, 0, stream>>>(key_,  ipw + 1 * EMB * EMB, ipb + EMB,   kbuf,
                                          L_NODES, EMB, EMB, 1.f);
        gemm_bt<<<gblk, 256, 0, stream>>>(value, ipw + 2 * EMB * EMB, ipb + 2*EMB, vbuf,
                                          L_NODES, EMB, EMB, 1.f);
        edge_attn<<<L_NODES, 512, 0, stream>>>(qbuf, kbuf, vbuf, indices + NNZ_E, qbuf);
        gemm_bt<<<gblk, 256, 0, stream>>>(qbuf, opw, opb, out, L_NODES, EMB, EMB, 1.f);
    }
}

// Round 10
// 142.032 us; speedup vs baseline: 1.1326x; 1.0285x over previous
//
#include <hip/hip_runtime.h>
#include <math.h>

#define L_NODES 16384
#define EMB 512
#define NHEAD 8
#define HDIM 64
#define DEG 16
#define NNZ_E (L_NODES * DEG)

typedef __attribute__((ext_vector_type(8))) short short8;
typedef __attribute__((ext_vector_type(4))) float f32x4;

// ---------------- fp32 -> bf16 convert (RNE) ----------------
__device__ inline short f2bs(float x) {
    union { float f; unsigned u; } c; c.f = x;
    unsigned r = (c.u + 0x7fffu + ((c.u >> 16) & 1u)) >> 16;
    return (short)r;
}

__device__ inline void cv8(const float* __restrict__ s, short* __restrict__ d, int i) {
    float4 a = reinterpret_cast<const float4*>(s)[2 * i];
    float4 b = reinterpret_cast<const float4*>(s)[2 * i + 1];
    short8 o;
    o[0] = f2bs(a.x); o[1] = f2bs(a.y); o[2] = f2bs(a.z); o[3] = f2bs(a.w);
    o[4] = f2bs(b.x); o[5] = f2bs(b.y); o[6] = f2bs(b.z); o[7] = f2bs(b.w);
    reinterpret_cast<short8*>(d)[i] = o;
}

__global__ __launch_bounds__(256) void f2bw(
    const float* __restrict__ w1, short* __restrict__ d1, int n1,
    const float* __restrict__ w2, short* __restrict__ d2, int n2) {
    const int stride = gridDim.x * blockDim.x;
    for (int i = blockIdx.x * blockDim.x + threadIdx.x; i < n1 + n2; i += stride) {
        if (i < n1) cv8(w1, d1, i); else cv8(w2, d2, i - n1);
    }
}

// bf16x8 (as short8) -> 8 floats
__device__ inline void b2f8(short8 s, float* f) {
    const unsigned* u = reinterpret_cast<const unsigned*>(&s);
#pragma unroll
    for (int j = 0; j < 4; ++j) {
        unsigned lo = u[j] << 16;
        unsigned hi = u[j] & 0xFFFF0000u;
        f[2 * j]     = __builtin_bit_cast(float, lo);
        f[2 * j + 1] = __builtin_bit_cast(float, hi);
    }
}

__device__ inline void gload16(const short* g, short* l) {
    __builtin_amdgcn_global_load_lds(
        (const __attribute__((address_space(1))) unsigned*)g,
        (__attribute__((address_space(3))) unsigned*)l, 16, 0, 0);
}

__device__ inline short8 cvt16(float4 a0, float4 a1) {
    short8 s;
    s[0] = f2bs(a0.x); s[1] = f2bs(a0.y); s[2] = f2bs(a0.z); s[3] = f2bs(a0.w);
    s[4] = f2bs(a1.x); s[5] = f2bs(a1.y); s[6] = f2bs(a1.z); s[7] = f2bs(a1.w);
    return s;
}

// ---------------- fused QKV GEMM, 128x256 tile ----------------
// A re-read amplification: BN=256 -> each fp32 input read only 2x (was 4x),
// halving the dominant L2/L3 A-stream. 512 thr / 8 waves (2 row x 4 col
// quadrants of 64x64). GBK=32 single-buffered: LDS 24 KB, grid 768 = 3/CU.
#define QBM 128
#define QBN 256
#define QBK 32

__global__ __launch_bounds__(512) void gemm_qkv(
    const float* __restrict__ q_in, const float* __restrict__ k_in,
    const float* __restrict__ v_in, const short* __restrict__ wqkv,
    const float* __restrict__ bias_all,
    short* __restrict__ qo, short* __restrict__ ko, short* __restrict__ vo)
{
    __shared__ __align__(16) short As[QBM * QBK];   // 8 KB
    __shared__ __align__(16) short Bs[QBN * QBK];   // 16 KB

    const int gid   = blockIdx.x;
    const int which = gid >> 8;            // 256 blocks per GEMM
    const int inner = gid & 255;

    const float* A    = which == 0 ? q_in : (which == 1 ? k_in : v_in);
    const short* B    = wqkv + which * 262144;
    const float* bias = bias_all + which * 512;
    short*       C    = which == 0 ? qo : (which == 1 ? ko : vo);
    const float scale = which == 0 ? 0.125f : 1.0f;

    const int t    = threadIdx.x;
    const int wid  = t >> 6;               // 0..7
    const int lane = t & 63;

    // XCD swizzle (256 = 8 * 32, bijective)
    const int wg = (inner & 7) * 32 + (inner >> 3);
    const int bx = wg & 1;
    const int by = wg >> 1;
    const int row0 = by * QBM;
    const int col0 = bx * QBN;

    // A staging: thread -> (row ar = t>>2, phys 16B-slot t&3); source fetches
    // logical slot (t&3)^x(ar) so the read-side phys = logical^x sees its data.
    const int ar  = t >> 2;
    const int asl = (t & 3) ^ ((ar >> 1) & 3);
    const float* Agp = A + (size_t)(row0 + ar) * 512 + asl * 8;
    short* awp = &As[ar * QBK + (t & 3) * 8];

    // B staging via global_load_lds (source-address swizzle, linear LDS).
    // Wave w covers rows w*16..w*16+15 per gload (4 lanes x 16B per row).
    const int br0 = t >> 2;
    const int bs0 = (t & 3) ^ ((br0 >> 1) & 3);
    const int br1 = 128 + br0;             // x(br1)==x(br0), kept explicit
    const int bs1 = (t & 3) ^ ((br1 >> 1) & 3);
    const short* Bg0 = B + (size_t)(col0 + br0) * 512 + bs0 * 8;
    const short* Bg1 = B + (size_t)(col0 + br1) * 512 + bs1 * 8;
    short* Bl0 = &Bs[wid * 512];
    short* Bl1 = &Bs[4096 + wid * 512];

    const int wr = wid >> 2;               // 0..1 row half
    const int wc = wid & 3;                // 0..3 col quarter

    f32x4 acc[4][4] = {};

    for (int k0 = 0; k0 < 512; k0 += QBK) {
        gload16(Bg0 + k0, Bl0);
        gload16(Bg1 + k0, Bl1);
        float4 a0 = *reinterpret_cast<const float4*>(Agp + k0);
        float4 a1 = *reinterpret_cast<const float4*>(Agp + k0 + 4);
        *reinterpret_cast<short8*>(awp) = cvt16(a0, a1);
        __syncthreads();

        short8 af[4], bf[4];
#pragma unroll
        for (int i = 0; i < 4; ++i) {
            const int r  = wr * 64 + i * 16 + (lane & 15);
            const int sl = (lane >> 4) ^ ((r >> 1) & 3);
            af[i] = *reinterpret_cast<const short8*>(&As[r * QBK + sl * 8]);
        }
#pragma unroll
        for (int j = 0; j < 4; ++j) {
            const int r  = wc * 64 + j * 16 + (lane & 15);
            const int sl = (lane >> 4) ^ ((r >> 1) & 3);
            bf[j] = *reinterpret_cast<const short8*>(&Bs[r * QBK + sl * 8]);
        }
#pragma unroll
        for (int i = 0; i < 4; ++i)
#pragma unroll
            for (int j = 0; j < 4; ++j)
                acc[i][j] = __builtin_amdgcn_mfma_f32_16x16x32_bf16(
                    af[i], bf[j], acc[i][j], 0, 0, 0);
        __syncthreads();
    }

    float bv[4];
#pragma unroll
    for (int j = 0; j < 4; ++j) bv[j] = bias[col0 + wc * 64 + j * 16 + (lane & 15)];
#pragma unroll
    for (int i = 0; i < 4; ++i) {
        const int rbase = row0 + wr * 64 + i * 16 + (lane >> 4) * 4;
#pragma unroll
        for (int j = 0; j < 4; ++j) {
            const int col = col0 + wc * 64 + j * 16 + (lane & 15);
#pragma unroll
            for (int rg = 0; rg < 4; ++rg)
                C[(size_t)(rbase + rg) * 512 + col] =
                    f2bs((acc[i][j][rg] + bv[j]) * scale);
        }
    }
}

// ---------------- out-proj GEMM (bf16 A via global_load_lds, fp32 out) ----------------
#define BM 128
#define BN 128
#define GBK 32

__global__ __launch_bounds__(256) void gemm_out(
    const short* __restrict__ A, const short* __restrict__ B,
    const float* __restrict__ bias, float* __restrict__ C)
{
    __shared__ __align__(16) short As[BM * GBK];
    __shared__ __align__(16) short Bs[BN * GBK];

    const int t    = threadIdx.x;
    const int wid  = t >> 6;
    const int lane = t & 63;

    const int cpx = gridDim.x >> 3;
    const int bid = blockIdx.x;
    const int wg  = (bid & 7) * cpx + (bid >> 3);
    const int bx  = wg & 3;
    const int by  = wg >> 2;
    const int row0 = by * BM;
    const int col0 = bx * BN;

    const int sr = t >> 2;
    const int ss = (t & 3) ^ ((sr >> 1) & 3);
    const short* Ag0 = A + (size_t)(row0 + sr) * 512 + ss * 8;
    const short* Ag1 = A + (size_t)(row0 + 64 + sr) * 512 + ss * 8;
    const short* Bg0 = B + (size_t)(col0 + sr) * 512 + ss * 8;
    const short* Bg1 = B + (size_t)(col0 + 64 + sr) * 512 + ss * 8;
    short* Al0 = &As[wid * 512];
    short* Al1 = &As[2048 + wid * 512];
    short* Bl0 = &Bs[wid * 512];
    short* Bl1 = &Bs[2048 + wid * 512];

    const int wr = wid >> 1, wc = wid & 1;

    f32x4 acc[4][4] = {};

    for (int k0 = 0; k0 < 512; k0 += GBK) {
        gload16(Ag0 + k0, Al0);
        gload16(Ag1 + k0, Al1);
        gload16(Bg0 + k0, Bl0);
        gload16(Bg1 + k0, Bl1);
        __syncthreads();

        short8 af[4], bf[4];
#pragma unroll
        for (int i = 0; i < 4; ++i) {
            const int r  = wr * 64 + i * 16 + (lane & 15);
            const int sl = (lane >> 4) ^ ((r >> 1) & 3);
            af[i] = *reinterpret_cast<const short8*>(&As[r * GBK + sl * 8]);
        }
#pragma unroll
        for (int j = 0; j < 4; ++j) {
            const int r  = wc * 64 + j * 16 + (lane & 15);
            const int sl = (lane >> 4) ^ ((r >> 1) & 3);
            bf[j] = *reinterpret_cast<const short8*>(&Bs[r * GBK + sl * 8]);
        }
#pragma unroll
        for (int i = 0; i < 4; ++i)
#pragma unroll
            for (int j = 0; j < 4; ++j)
                acc[i][j] = __builtin_amdgcn_mfma_f32_16x16x32_bf16(
                    af[i], bf[j], acc[i][j], 0, 0, 0);
        __syncthreads();
    }

    float bv[4];
#pragma unroll
    for (int j = 0; j < 4; ++j) bv[j] = bias[col0 + wc * 64 + j * 16 + (lane & 15)];
#pragma unroll
    for (int i = 0; i < 4; ++i) {
        const int rbase = row0 + wr * 64 + i * 16 + (lane >> 4) * 4;
#pragma unroll
        for (int j = 0; j < 4; ++j) {
            const int col = col0 + wc * 64 + j * 16 + (lane & 15);
#pragma unroll
            for (int rg = 0; rg < 4; ++rg)
                C[(size_t)(rbase + rg) * 512 + col] = acc[i][j][rg] + bv[j];
        }
    }
}

// ---------------- edge softmax/aggregate, 2 nodes/block ----------------
__device__ inline float edge_core(const float* qf, short8 k0, short8 k1,
                                  short8 v0, short8 v1, int lane) {
    float kf0[8], kf1[8];
    b2f8(k0, kf0); b2f8(k1, kf1);
    float p0 = 0.f, p1 = 0.f;
#pragma unroll
    for (int j = 0; j < 8; ++j) { p0 += qf[j] * kf0[j]; p1 += qf[j] * kf1[j]; }

    const bool b0 = (lane & 1) != 0;
    float x = b0 ? p0 : p1;
    float r = __shfl_xor(x, 1, 64);
    float s = (b0 ? p1 : p0) + r;
    s += __shfl_xor(s, 2, 64);
    s += __shfl_xor(s, 4, 64);

    float m = s;
    m = fmaxf(m, __shfl_xor(m, 1, 64));
    m = fmaxf(m, __shfl_xor(m, 8, 64));
    m = fmaxf(m, __shfl_xor(m, 16, 64));
    m = fmaxf(m, __shfl_xor(m, 32, 64));
    float w = expf(s - m);
    float den = w;
    den += __shfl_xor(den, 1, 64);
    den += __shfl_xor(den, 8, 64);
    den += __shfl_xor(den, 16, 64);
    den += __shfl_xor(den, 32, 64);
    w *= (1.0f / den);

    const int srcb = lane & 56;
    const float w0 = __shfl(w, srcb, 64);
    const float w1 = __shfl(w, srcb | 1, 64);

    float vf0[8], vf1[8], of[8];
    b2f8(v0, vf0); b2f8(v1, vf1);
#pragma unroll
    for (int j = 0; j < 8; ++j) of[j] = w0 * vf0[j] + w1 * vf1[j];

    const bool b3 = (lane & 8) != 0;
    float o4[4];
#pragma unroll
    for (int j = 0; j < 4; ++j) {
        float send = b3 ? of[j] : of[4 + j];
        float recv = __shfl_xor(send, 8, 64);
        o4[j] = (b3 ? of[4 + j] : of[j]) + recv;
    }
    const bool b4 = (lane & 16) != 0;
    float z0 = __shfl_xor(b4 ? o4[0] : o4[2], 16, 64);
    float z1 = __shfl_xor(b4 ? o4[1] : o4[3], 16, 64);
    float t0 = (b4 ? o4[2] : o4[0]) + z0;
    float t1 = (b4 ? o4[3] : o4[1]) + z1;
    const bool b5 = (lane & 32) != 0;
    float zz = __shfl_xor(b5 ? t0 : t1, 32, 64);
    return (b5 ? t1 : t0) + zz;
}

__global__ __launch_bounds__(512) void edge_attn4(
    const short* __restrict__ qm, const short* __restrict__ km,
    const short* __restrict__ vm, const int* __restrict__ colidx,
    short* __restrict__ outb)
{
    const int i0   = blockIdx.x << 1;
    const int h    = threadIdx.x >> 6;
    const int lane = threadIdx.x & 63;
    const int c    = lane & 7;
    const int g    = lane >> 3;

    int creg = 0;
    if (lane < 2 * DEG) creg = colidx[i0 * DEG + lane];
    const int ca0 = __shfl(creg, g, 64);
    const int ca1 = __shfl(creg, g + 8, 64);
    const int cb0 = __shfl(creg, 16 + g, 64);
    const int cb1 = __shfl(creg, 16 + g + 8, 64);

    const size_t dof = (size_t)h * HDIM + 8 * c;
    short8 qA  = *reinterpret_cast<const short8*>(&qm[(size_t)i0 * EMB + dof]);
    short8 qB  = *reinterpret_cast<const short8*>(&qm[(size_t)(i0 + 1) * EMB + dof]);
    short8 kA0 = *reinterpret_cast<const short8*>(&km[(size_t)ca0 * EMB + dof]);
    short8 kA1 = *reinterpret_cast<const short8*>(&km[(size_t)ca1 * EMB + dof]);
    short8 kB0 = *reinterpret_cast<const short8*>(&km[(size_t)cb0 * EMB + dof]);
    short8 kB1 = *reinterpret_cast<const short8*>(&km[(size_t)cb1 * EMB + dof]);
    short8 vA0 = *reinterpret_cast<const short8*>(&vm[(size_t)ca0 * EMB + dof]);
    short8 vA1 = *reinterpret_cast<const short8*>(&vm[(size_t)ca1 * EMB + dof]);
    short8 vB0 = *reinterpret_cast<const short8*>(&vm[(size_t)cb0 * EMB + dof]);
    short8 vB1 = *reinterpret_cast<const short8*>(&vm[(size_t)cb1 * EMB + dof]);

    float qfA[8], qfB[8];
    b2f8(qA, qfA); b2f8(qB, qfB);

    const float oA = edge_core(qfA, kA0, kA1, vA0, vA1, lane);
    const float oB = edge_core(qfB, kB0, kB1, vB0, vB1, lane);

    const int d = 8 * c + ((lane & 8) ? 4 : 0) + ((lane & 16) ? 2 : 0)
                        + ((lane & 32) ? 1 : 0);
    outb[(size_t)i0 * EMB + h * HDIM + d]       = f2bs(oA);
    outb[(size_t)(i0 + 1) * EMB + h * HDIM + d] = f2bs(oB);
}

// ---------------- fp32 fallback path ----------------
#define TILE 64
#define BKK 16
#define PAD_LD 68

__global__ __launch_bounds__(256) void gemm_bt(
    const float* __restrict__ A, const float* __restrict__ W,
    const float* __restrict__ bias, float* __restrict__ C,
    int M, int K, int N, float scale)
{
    __shared__ float Asm[BKK][PAD_LD];
    __shared__ float Bsm[BKK][PAD_LD];
    const int t  = threadIdx.x;
    const int tx = t & 15;
    const int ty = t >> 4;
    const int row0 = blockIdx.y * TILE;
    const int col0 = blockIdx.x * TILE;
    const int lr = t >> 2;
    const int lk = (t & 3) << 2;
    const float* Aptr = A + (size_t)(row0 + lr) * K + lk;
    const float* Wptr = W + (size_t)(col0 + lr) * K + lk;
    float acc[4][4] = {};
    for (int k0 = 0; k0 < K; k0 += BKK) {
        float4 a4 = *reinterpret_cast<const float4*>(Aptr + k0);
        float4 b4 = *reinterpret_cast<const float4*>(Wptr + k0);
        Asm[lk + 0][lr] = a4.x; Asm[lk + 1][lr] = a4.y;
        Asm[lk + 2][lr] = a4.z; Asm[lk + 3][lr] = a4.w;
        Bsm[lk + 0][lr] = b4.x; Bsm[lk + 1][lr] = b4.y;
        Bsm[lk + 2][lr] = b4.z; Bsm[lk + 3][lr] = b4.w;
        __syncthreads();
#pragma unroll
        for (int kk = 0; kk < BKK; ++kk) {
            float a[4], b[4];
#pragma unroll
            for (int i2 = 0; i2 < 4; ++i2) a[i2] = Asm[kk][ty * 4 + i2];
#pragma unroll
            for (int j2 = 0; j2 < 4; ++j2) b[j2] = Bsm[kk][tx * 4 + j2];
#pragma unroll
            for (int i2 = 0; i2 < 4; ++i2)
#pragma unroll
                for (int j2 = 0; j2 < 4; ++j2)
                    acc[i2][j2] += a[i2] * b[j2];
        }
        __syncthreads();
    }
#pragma unroll
    for (int i2 = 0; i2 < 4; ++i2) {
        const int r = row0 + ty * 4 + i2;
        float4 o;
        o.x = (acc[i2][0] + bias[col0 + tx * 4 + 0]) * scale;
        o.y = (acc[i2][1] + bias[col0 + tx * 4 + 1]) * scale;
        o.z = (acc[i2][2] + bias[col0 + tx * 4 + 2]) * scale;
        o.w = (acc[i2][3] + bias[col0 + tx * 4 + 3]) * scale;
        *reinterpret_cast<float4*>(&C[(size_t)r * N + col0 + tx * 4]) = o;
    }
}

__global__ __launch_bounds__(512) void edge_attn(
    const float* q, const float* __restrict__ kmat, const float* __restrict__ vmat,
    const int* __restrict__ colidx, float* out)
{
    const int i    = blockIdx.x;
    const int h    = threadIdx.x >> 6;
    const int lane = threadIdx.x & 63;
    const size_t base = (size_t)i * EMB + h * HDIM + lane;

    const float qd = q[base];
    int creg = 0;
    if (lane < DEG) creg = colidx[i * DEG + lane];

    float kr[DEG], vr[DEG];
#pragma unroll
    for (int e = 0; e < DEG; ++e) {
        const int ce = __shfl(creg, e, 64);
        const size_t cb = (size_t)ce * EMB + h * HDIM + lane;
        kr[e] = kmat[cb];
        vr[e] = vmat[cb];
    }
    float s[DEG];
#pragma unroll
    for (int e = 0; e < DEG; ++e) {
        float p = qd * kr[e];
#pragma unroll
        for (int off = 32; off; off >>= 1) p += __shfl_xor(p, off, 64);
        s[e] = p;
    }
    float m = s[0];
#pragma unroll
    for (int e = 1; e < DEG; ++e) m = fmaxf(m, s[e]);
    float denom = 0.f;
#pragma unroll
    for (int e = 0; e < DEG; ++e) { s[e] = expf(s[e] - m); denom += s[e]; }
    const float inv = 1.f / denom;
    float o = 0.f;
#pragma unroll
    for (int e = 0; e < DEG; ++e) o += s[e] * vr[e];
    out[base] = o * inv;
}

extern "C" void kernel_launch(void* const* d_in, const int* in_sizes, int n_in,
                              void* d_out, int out_size, void* d_ws, size_t ws_size,
                              hipStream_t stream) {
    const float* query   = (const float*)d_in[0];
    const float* key_    = (const float*)d_in[1];
    const float* value   = (const float*)d_in[2];
    const int*   indices = (const int*)  d_in[3];
    const float* ipw     = (const float*)d_in[4];
    const float* ipb     = (const float*)d_in[5];
    const float* opw     = (const float*)d_in[6];
    const float* opb     = (const float*)d_in[7];
    float* out = (float*)d_out;

    const size_t NEED = 70000000;  // shorts: wqkv+wo+qo+ko+vo+ab = 69.2 MB

    if (ws_size >= NEED) {
        short* wqkv = (short*)d_ws;          // 786432
        short* wo   = wqkv + 786432;         // 262144
        short* qo   = wo + 262144;           // 8388608 each
        short* ko   = qo + 8388608;
        short* vo   = ko + 8388608;
        short* ab   = vo + 8388608;          // attn out bf16

        f2bw<<<512, 256, 0, stream>>>(ipw, wqkv, 98304, opw, wo, 32768);
        gemm_qkv<<<768, 512, 0, stream>>>(query, key_, value, wqkv, ipb,
                                          qo, ko, vo);
        edge_attn4<<<L_NODES / 2, 512, 0, stream>>>(qo, ko, vo,
                                                    indices + NNZ_E, ab);
        gemm_out<<<512, 256, 0, stream>>>(ab, wo, opb, out);
    } else {
        float* qbuf = (float*)d_ws;
        float* kbuf = qbuf + (size_t)L_NODES * EMB;
        float* vbuf = kbuf + (size_t)L_NODES * EMB;
        const dim3 gblk(EMB / TILE, L_NODES / TILE);
        const float scaling = 0.125f;
        gemm_bt<<<gblk, 256, 0, stream>>>(query, ipw,                 ipb,         qbuf,
                                          L_NODES, EMB, EMB, scaling);
        gemm_bt<<<gblk, 256, 0, stream>>>(key_,  ipw + 1 * EMB * EMB, ipb + EMB,   kbuf,
                                          L_NODES, EMB, EMB, 1.f);
        gemm_bt<<<gblk, 256, 0, stream>>>(value, ipw + 2 * EMB * EMB, ipb + 2*EMB, vbuf,
                                          L_NODES, EMB, EMB, 1.f);
        edge_attn<<<L_NODES, 512, 0, stream>>>(qbuf, kbuf, vbuf, indices + NNZ_E, qbuf);
        gemm_bt<<<gblk, 256, 0, stream>>>(qbuf, opw, opb, out, L_NODES, EMB, EMB, 1.f);
    }
}

// Round 11
// 141.044 us; speedup vs baseline: 1.1406x; 1.0070x over previous
//
#include <hip/hip_runtime.h>
#include <math.h>

#define L_NODES 16384
#define EMB 512
#define NHEAD 8
#define HDIM 64
#define DEG 16
#define NNZ_E (L_NODES * DEG)

typedef __attribute__((ext_vector_type(8))) short short8;
typedef __attribute__((ext_vector_type(4))) float f32x4;

// ---------------- fp32 -> bf16 convert (RNE) ----------------
__device__ inline short f2bs(float x) {
    union { float f; unsigned u; } c; c.f = x;
    unsigned r = (c.u + 0x7fffu + ((c.u >> 16) & 1u)) >> 16;
    return (short)r;
}

__device__ inline void cv8(const float* __restrict__ s, short* __restrict__ d, int i) {
    float4 a = reinterpret_cast<const float4*>(s)[2 * i];
    float4 b = reinterpret_cast<const float4*>(s)[2 * i + 1];
    short8 o;
    o[0] = f2bs(a.x); o[1] = f2bs(a.y); o[2] = f2bs(a.z); o[3] = f2bs(a.w);
    o[4] = f2bs(b.x); o[5] = f2bs(b.y); o[6] = f2bs(b.z); o[7] = f2bs(b.w);
    reinterpret_cast<short8*>(d)[i] = o;
}

__global__ __launch_bounds__(256) void f2bw(
    const float* __restrict__ w1, short* __restrict__ d1, int n1,
    const float* __restrict__ w2, short* __restrict__ d2, int n2) {
    const int stride = gridDim.x * blockDim.x;
    for (int i = blockIdx.x * blockDim.x + threadIdx.x; i < n1 + n2; i += stride) {
        if (i < n1) cv8(w1, d1, i); else cv8(w2, d2, i - n1);
    }
}

// bf16x8 (as short8) -> 8 floats
__device__ inline void b2f8(short8 s, float* f) {
    const unsigned* u = reinterpret_cast<const unsigned*>(&s);
#pragma unroll
    for (int j = 0; j < 4; ++j) {
        unsigned lo = u[j] << 16;
        unsigned hi = u[j] & 0xFFFF0000u;
        f[2 * j]     = __builtin_bit_cast(float, lo);
        f[2 * j + 1] = __builtin_bit_cast(float, hi);
    }
}

__device__ inline void gload16(const short* g, short* l) {
    __builtin_amdgcn_global_load_lds(
        (const __attribute__((address_space(1))) unsigned*)g,
        (__attribute__((address_space(3))) unsigned*)l, 16, 0, 0);
}

__device__ inline short8 cvt16(float4 a0, float4 a1) {
    short8 s;
    s[0] = f2bs(a0.x); s[1] = f2bs(a0.y); s[2] = f2bs(a0.z); s[3] = f2bs(a0.w);
    s[4] = f2bs(a1.x); s[5] = f2bs(a1.y); s[6] = f2bs(a1.z); s[7] = f2bs(a1.w);
    return s;
}

// 3-bit slot swizzle: phys = logical ^ x(row). Spreads the 8 16B-slots of a
// 128B row across all 32 banks for ds_read_b128 (2 lanes/bank = free).
__device__ inline int swz8(int r) { return ((r >> 1) & 3) | ((r & 1) << 2); }

// ---------------- fused QKV GEMM: 128x256 tile, BK=64 ----------------
// 8 K-steps (was 16): half the barrier drains, 2x memory-level parallelism
// per phase (4 B-gloads + 4 A-float4 in flight per thread).
#define QBM 128
#define QBN 256
#define QBK 64

__global__ __launch_bounds__(512) void gemm_qkv(
    const float* __restrict__ q_in, const float* __restrict__ k_in,
    const float* __restrict__ v_in, const short* __restrict__ wqkv,
    const float* __restrict__ bias_all,
    short* __restrict__ qo, short* __restrict__ ko, short* __restrict__ vo)
{
    __shared__ __align__(16) short As[QBM * QBK];   // 16 KB
    __shared__ __align__(16) short Bs[QBN * QBK];   // 32 KB

    const int gid   = blockIdx.x;
    const int which = gid >> 8;            // 256 blocks per GEMM
    const int inner = gid & 255;

    const float* A    = which == 0 ? q_in : (which == 1 ? k_in : v_in);
    const short* B    = wqkv + which * 262144;
    const float* bias = bias_all + which * 512;
    short*       C    = which == 0 ? qo : (which == 1 ? ko : vo);
    const float scale = which == 0 ? 0.125f : 1.0f;

    const int t    = threadIdx.x;
    const int wid  = t >> 6;               // 0..7
    const int lane = t & 63;

    const int wg = (inner & 7) * 32 + (inner >> 3);
    const int bx = wg & 1;
    const int by = wg >> 1;
    const int row0 = by * QBM;
    const int col0 = bx * QBN;

    // A staging: thread -> (row ar=t>>2, phys slots 2q,2q+1). Source reads the
    // LOGICAL slots (phys ^ x) so ds_read's phys = logical ^ x finds its data.
    const int ar  = t >> 2;
    const int q2  = (t & 3) << 1;
    const int xa  = swz8(ar);
    const int la0 = q2 ^ xa;
    const int la1 = (q2 + 1) ^ xa;
    const float* Aga = A + (size_t)(row0 + ar) * 512;
    short* awp0 = &As[ar * QBK + q2 * 8];
    short* awp1 = awp0 + 8;

    // B staging via global_load_lds: 4 issues/thread, rows (t>>3)+j*64,
    // phys slot t&7, source column swizzled (j*64 == 0 mod 8 -> same x).
    const int brw = t >> 3;                // 0..63
    const int bp  = t & 7;
    const int xb  = swz8(brw & 7);
    const short* Bgb = B + (size_t)(col0 + brw) * 512 + (bp ^ xb) * 8;
    short* Bld = &Bs[(wid * 8) * QBK];     // wave-uniform base; +j*64*QBK per j

    const int wr = wid >> 2;               // 0..1
    const int wc = wid & 3;                // 0..3

    f32x4 acc[4][4] = {};

    for (int k0 = 0; k0 < 512; k0 += QBK) {
#pragma unroll
        for (int j = 0; j < 4; ++j)
            gload16(Bgb + (size_t)j * 64 * 512 + k0, Bld + j * 64 * QBK);
        {
            const float* ap0 = Aga + la0 * 8 + k0;
            const float* ap1 = Aga + la1 * 8 + k0;
            float4 a0 = *reinterpret_cast<const float4*>(ap0);
            float4 a1 = *reinterpret_cast<const float4*>(ap0 + 4);
            float4 a2 = *reinterpret_cast<const float4*>(ap1);
            float4 a3 = *reinterpret_cast<const float4*>(ap1 + 4);
            *reinterpret_cast<short8*>(awp0) = cvt16(a0, a1);
            *reinterpret_cast<short8*>(awp1) = cvt16(a2, a3);
        }
        __syncthreads();

#pragma unroll
        for (int kk = 0; kk < 2; ++kk) {
            short8 af[4], bf[4];
#pragma unroll
            for (int i = 0; i < 4; ++i) {
                const int r  = wr * 64 + i * 16 + (lane & 15);
                const int sl = (kk * 4 + (lane >> 4)) ^ swz8(r);
                af[i] = *reinterpret_cast<const short8*>(&As[r * QBK + sl * 8]);
            }
#pragma unroll
            for (int j = 0; j < 4; ++j) {
                const int r  = wc * 64 + j * 16 + (lane & 15);
                const int sl = (kk * 4 + (lane >> 4)) ^ swz8(r);
                bf[j] = *reinterpret_cast<const short8*>(&Bs[r * QBK + sl * 8]);
            }
#pragma unroll
            for (int i = 0; i < 4; ++i)
#pragma unroll
                for (int j = 0; j < 4; ++j)
                    acc[i][j] = __builtin_amdgcn_mfma_f32_16x16x32_bf16(
                        af[i], bf[j], acc[i][j], 0, 0, 0);
        }
        __syncthreads();
    }

    float bv[4];
#pragma unroll
    for (int j = 0; j < 4; ++j) bv[j] = bias[col0 + wc * 64 + j * 16 + (lane & 15)];
#pragma unroll
    for (int i = 0; i < 4; ++i) {
        const int rbase = row0 + wr * 64 + i * 16 + (lane >> 4) * 4;
#pragma unroll
        for (int j = 0; j < 4; ++j) {
            const int col = col0 + wc * 64 + j * 16 + (lane & 15);
#pragma unroll
            for (int rg = 0; rg < 4; ++rg)
                C[(size_t)(rbase + rg) * 512 + col] =
                    f2bs((acc[i][j][rg] + bv[j]) * scale);
        }
    }
}

// ---------------- out-proj GEMM: 128x128, BK=64, both operands gload_lds ----------------
#define OBK 64

__global__ __launch_bounds__(256) void gemm_out(
    const short* __restrict__ A, const short* __restrict__ B,
    const float* __restrict__ bias, float* __restrict__ C)
{
    __shared__ __align__(16) short As[128 * OBK];   // 16 KB
    __shared__ __align__(16) short Bs[128 * OBK];   // 16 KB

    const int t    = threadIdx.x;
    const int wid  = t >> 6;               // 0..3
    const int lane = t & 63;

    const int cpx = gridDim.x >> 3;
    const int bid = blockIdx.x;
    const int wg  = (bid & 7) * cpx + (bid >> 3);
    const int bx  = wg & 3;
    const int by  = wg >> 2;
    const int row0 = by * 128;
    const int col0 = bx * 128;

    // staging: 4 gloads per operand per thread; rows (t>>3)+j*32, slot t&7
    const int rw = t >> 3;                 // 0..31
    const int p  = t & 7;
    const int xs = swz8(rw & 7);
    const short* AgS = A + (size_t)(row0 + rw) * 512 + (p ^ xs) * 8;
    const short* BgS = B + (size_t)(col0 + rw) * 512 + (p ^ xs) * 8;
    short* Ald = &As[(wid * 8) * OBK];
    short* Bld = &Bs[(wid * 8) * OBK];

    const int wr = wid >> 1, wc = wid & 1;

    f32x4 acc[4][4] = {};

    for (int k0 = 0; k0 < 512; k0 += OBK) {
#pragma unroll
        for (int j = 0; j < 4; ++j) {
            gload16(AgS + (size_t)j * 32 * 512 + k0, Ald + j * 32 * OBK);
            gload16(BgS + (size_t)j * 32 * 512 + k0, Bld + j * 32 * OBK);
        }
        __syncthreads();

#pragma unroll
        for (int kk = 0; kk < 2; ++kk) {
            short8 af[4], bf[4];
#pragma unroll
            for (int i = 0; i < 4; ++i) {
                const int r  = wr * 64 + i * 16 + (lane & 15);
                const int sl = (kk * 4 + (lane >> 4)) ^ swz8(r);
                af[i] = *reinterpret_cast<const short8*>(&As[r * OBK + sl * 8]);
            }
#pragma unroll
            for (int j = 0; j < 4; ++j) {
                const int r  = wc * 64 + j * 16 + (lane & 15);
                const int sl = (kk * 4 + (lane >> 4)) ^ swz8(r);
                bf[j] = *reinterpret_cast<const short8*>(&Bs[r * OBK + sl * 8]);
            }
#pragma unroll
            for (int i = 0; i < 4; ++i)
#pragma unroll
                for (int j = 0; j < 4; ++j)
                    acc[i][j] = __builtin_amdgcn_mfma_f32_16x16x32_bf16(
                        af[i], bf[j], acc[i][j], 0, 0, 0);
        }
        __syncthreads();
    }

    float bv[4];
#pragma unroll
    for (int j = 0; j < 4; ++j) bv[j] = bias[col0 + wc * 64 + j * 16 + (lane & 15)];
#pragma unroll
    for (int i = 0; i < 4; ++i) {
        const int rbase = row0 + wr * 64 + i * 16 + (lane >> 4) * 4;
#pragma unroll
        for (int j = 0; j < 4; ++j) {
            const int col = col0 + wc * 64 + j * 16 + (lane & 15);
#pragma unroll
            for (int rg = 0; rg < 4; ++rg)
                C[(size_t)(rbase + rg) * 512 + col] = acc[i][j][rg] + bv[j];
        }
    }
}

// ---------------- edge softmax/aggregate, 2 nodes/block ----------------
__device__ inline float edge_core(const float* qf, short8 k0, short8 k1,
                                  short8 v0, short8 v1, int lane) {
    float kf0[8], kf1[8];
    b2f8(k0, kf0); b2f8(k1, kf1);
    float p0 = 0.f, p1 = 0.f;
#pragma unroll
    for (int j = 0; j < 8; ++j) { p0 += qf[j] * kf0[j]; p1 += qf[j] * kf1[j]; }

    const bool b0 = (lane & 1) != 0;
    float x = b0 ? p0 : p1;
    float r = __shfl_xor(x, 1, 64);
    float s = (b0 ? p1 : p0) + r;
    s += __shfl_xor(s, 2, 64);
    s += __shfl_xor(s, 4, 64);

    float m = s;
    m = fmaxf(m, __shfl_xor(m, 1, 64));
    m = fmaxf(m, __shfl_xor(m, 8, 64));
    m = fmaxf(m, __shfl_xor(m, 16, 64));
    m = fmaxf(m, __shfl_xor(m, 32, 64));
    float w = expf(s - m);
    float den = w;
    den += __shfl_xor(den, 1, 64);
    den += __shfl_xor(den, 8, 64);
    den += __shfl_xor(den, 16, 64);
    den += __shfl_xor(den, 32, 64);
    w *= (1.0f / den);

    const int srcb = lane & 56;
    const float w0 = __shfl(w, srcb, 64);
    const float w1 = __shfl(w, srcb | 1, 64);

    float vf0[8], vf1[8], of[8];
    b2f8(v0, vf0); b2f8(v1, vf1);
#pragma unroll
    for (int j = 0; j < 8; ++j) of[j] = w0 * vf0[j] + w1 * vf1[j];

    const bool b3 = (lane & 8) != 0;
    float o4[4];
#pragma unroll
    for (int j = 0; j < 4; ++j) {
        float send = b3 ? of[j] : of[4 + j];
        float recv = __shfl_xor(send, 8, 64);
        o4[j] = (b3 ? of[4 + j] : of[j]) + recv;
    }
    const bool b4 = (lane & 16) != 0;
    float z0 = __shfl_xor(b4 ? o4[0] : o4[2], 16, 64);
    float z1 = __shfl_xor(b4 ? o4[1] : o4[3], 16, 64);
    float t0 = (b4 ? o4[2] : o4[0]) + z0;
    float t1 = (b4 ? o4[3] : o4[1]) + z1;
    const bool b5 = (lane & 32) != 0;
    float zz = __shfl_xor(b5 ? t0 : t1, 32, 64);
    return (b5 ? t1 : t0) + zz;
}

__global__ __launch_bounds__(512) void edge_attn4(
    const short* __restrict__ qm, const short* __restrict__ km,
    const short* __restrict__ vm, const int* __restrict__ colidx,
    short* __restrict__ outb)
{
    const int i0   = blockIdx.x << 1;
    const int h    = threadIdx.x >> 6;
    const int lane = threadIdx.x & 63;
    const int c    = lane & 7;
    const int g    = lane >> 3;

    int creg = 0;
    if (lane < 2 * DEG) creg = colidx[i0 * DEG + lane];
    const int ca0 = __shfl(creg, g, 64);
    const int ca1 = __shfl(creg, g + 8, 64);
    const int cb0 = __shfl(creg, 16 + g, 64);
    const int cb1 = __shfl(creg, 16 + g + 8, 64);

    const size_t dof = (size_t)h * HDIM + 8 * c;
    short8 qA  = *reinterpret_cast<const short8*>(&qm[(size_t)i0 * EMB + dof]);
    short8 qB  = *reinterpret_cast<const short8*>(&qm[(size_t)(i0 + 1) * EMB + dof]);
    short8 kA0 = *reinterpret_cast<const short8*>(&km[(size_t)ca0 * EMB + dof]);
    short8 kA1 = *reinterpret_cast<const short8*>(&km[(size_t)ca1 * EMB + dof]);
    short8 kB0 = *reinterpret_cast<const short8*>(&km[(size_t)cb0 * EMB + dof]);
    short8 kB1 = *reinterpret_cast<const short8*>(&km[(size_t)cb1 * EMB + dof]);
    short8 vA0 = *reinterpret_cast<const short8*>(&vm[(size_t)ca0 * EMB + dof]);
    short8 vA1 = *reinterpret_cast<const short8*>(&vm[(size_t)ca1 * EMB + dof]);
    short8 vB0 = *reinterpret_cast<const short8*>(&vm[(size_t)cb0 * EMB + dof]);
    short8 vB1 = *reinterpret_cast<const short8*>(&vm[(size_t)cb1 * EMB + dof]);

    float qfA[8], qfB[8];
    b2f8(qA, qfA); b2f8(qB, qfB);

    const float oA = edge_core(qfA, kA0, kA1, vA0, vA1, lane);
    const float oB = edge_core(qfB, kB0, kB1, vB0, vB1, lane);

    const int d = 8 * c + ((lane & 8) ? 4 : 0) + ((lane & 16) ? 2 : 0)
                        + ((lane & 32) ? 1 : 0);
    outb[(size_t)i0 * EMB + h * HDIM + d]       = f2bs(oA);
    outb[(size_t)(i0 + 1) * EMB + h * HDIM + d] = f2bs(oB);
}

// ---------------- fp32 fallback path ----------------
#define TILE 64
#define BKK 16
#define PAD_LD 68

__global__ __launch_bounds__(256) void gemm_bt(
    const float* __restrict__ A, const float* __restrict__ W,
    const float* __restrict__ bias, float* __restrict__ C,
    int M, int K, int N, float scale)
{
    __shared__ float Asm[BKK][PAD_LD];
    __shared__ float Bsm[BKK][PAD_LD];
    const int t  = threadIdx.x;
    const int tx = t & 15;
    const int ty = t >> 4;
    const int row0 = blockIdx.y * TILE;
    const int col0 = blockIdx.x * TILE;
    const int lr = t >> 2;
    const int lk = (t & 3) << 2;
    const float* Aptr = A + (size_t)(row0 + lr) * K + lk;
    const float* Wptr = W + (size_t)(col0 + lr) * K + lk;
    float acc[4][4] = {};
    for (int k0 = 0; k0 < K; k0 += BKK) {
        float4 a4 = *reinterpret_cast<const float4*>(Aptr + k0);
        float4 b4 = *reinterpret_cast<const float4*>(Wptr + k0);
        Asm[lk + 0][lr] = a4.x; Asm[lk + 1][lr] = a4.y;
        Asm[lk + 2][lr] = a4.z; Asm[lk + 3][lr] = a4.w;
        Bsm[lk + 0][lr] = b4.x; Bsm[lk + 1][lr] = b4.y;
        Bsm[lk + 2][lr] = b4.z; Bsm[lk + 3][lr] = b4.w;
        __syncthreads();
#pragma unroll
        for (int kk = 0; kk < BKK; ++kk) {
            float a[4], b[4];
#pragma unroll
            for (int i2 = 0; i2 < 4; ++i2) a[i2] = Asm[kk][ty * 4 + i2];
#pragma unroll
            for (int j2 = 0; j2 < 4; ++j2) b[j2] = Bsm[kk][tx * 4 + j2];
#pragma unroll
            for (int i2 = 0; i2 < 4; ++i2)
#pragma unroll
                for (int j2 = 0; j2 < 4; ++j2)
                    acc[i2][j2] += a[i2] * b[j2];
        }
        __syncthreads();
    }
#pragma unroll
    for (int i2 = 0; i2 < 4; ++i2) {
        const int r = row0 + ty * 4 + i2;
        float4 o;
        o.x = (acc[i2][0] + bias[col0 + tx * 4 + 0]) * scale;
        o.y = (acc[i2][1] + bias[col0 + tx * 4 + 1]) * scale;
        o.z = (acc[i2][2] + bias[col0 + tx * 4 + 2]) * scale;
        o.w = (acc[i2][3] + bias[col0 + tx * 4 + 3]) * scale;
        *reinterpret_cast<float4*>(&C[(size_t)r * N + col0 + tx * 4]) = o;
    }
}

__global__ __launch_bounds__(512) void edge_attn(
    const float* q, const float* __restrict__ kmat, const float* __restrict__ vmat,
    const int* __restrict__ colidx, float* out)
{
    const int i    = blockIdx.x;
    const int h    = threadIdx.x >> 6;
    const int lane = threadIdx.x & 63;
    const size_t base = (size_t)i * EMB + h * HDIM + lane;

    const float qd = q[base];
    int creg = 0;
    if (lane < DEG) creg = colidx[i * DEG + lane];

    float kr[DEG], vr[DEG];
#pragma unroll
    for (int e = 0; e < DEG; ++e) {
        const int ce = __shfl(creg, e, 64);
        const size_t cb = (size_t)ce * EMB + h * HDIM + lane;
        kr[e] = kmat[cb];
        vr[e] = vmat[cb];
    }
    float s[DEG];
#pragma unroll
    for (int e = 0; e < DEG; ++e) {
        float p = qd * kr[e];
#pragma unroll
        for (int off = 32; off; off >>= 1) p += __shfl_xor(p, off, 64);
        s[e] = p;
    }
    float m = s[0];
#pragma unroll
    for (int e = 1; e < DEG; ++e) m = fmaxf(m, s[e]);
    float denom = 0.f;
#pragma unroll
    for (int e = 0; e < DEG; ++e) { s[e] = expf(s[e] - m); denom += s[e]; }
    const float inv = 1.f / denom;
    float o = 0.f;
#pragma unroll
    for (int e = 0; e < DEG; ++e) o += s[e] * vr[e];
    out[base] = o * inv;
}

extern "C" void kernel_launch(void* const* d_in, const int* in_sizes, int n_in,
                              void* d_out, int out_size, void* d_ws, size_t ws_size,
                              hipStream_t stream) {
    const float* query   = (const float*)d_in[0];
    const float* key_    = (const float*)d_in[1];
    const float* value   = (const float*)d_in[2];
    const int*   indices = (const int*)  d_in[3];
    const float* ipw     = (const float*)d_in[4];
    const float* ipb     = (const float*)d_in[5];
    const float* opw     = (const float*)d_in[6];
    const float* opb     = (const float*)d_in[7];
    float* out = (float*)d_out;

    const size_t NEED = 70000000;  // shorts: wqkv+wo+qo+ko+vo+ab = 69.2 MB

    if (ws_size >= NEED) {
        short* wqkv = (short*)d_ws;          // 786432
        short* wo   = wqkv + 786432;         // 262144
        short* qo   = wo + 262144;           // 8388608 each
        short* ko   = qo + 8388608;
        short* vo   = ko + 8388608;
        short* ab   = vo + 8388608;          // attn out bf16

        f2bw<<<512, 256, 0, stream>>>(ipw, wqkv, 98304, opw, wo, 32768);
        gemm_qkv<<<768, 512, 0, stream>>>(query, key_, value, wqkv, ipb,
                                          qo, ko, vo);
        edge_attn4<<<L_NODES / 2, 512, 0, stream>>>(qo, ko, vo,
                                                    indices + NNZ_E, ab);
        gemm_out<<<512, 256, 0, stream>>>(ab, wo, opb, out);
    } else {
        float* qbuf = (float*)d_ws;
        float* kbuf = qbuf + (size_t)L_NODES * EMB;
        float* vbuf = kbuf + (size_t)L_NODES * EMB;
        const dim3 gblk(EMB / TILE, L_NODES / TILE);
        const float scaling = 0.125f;
        gemm_bt<<<gblk, 256, 0, stream>>>(query, ipw,                 ipb,         qbuf,
                                          L_NODES, EMB, EMB, scaling);
        gemm_bt<<<gblk, 256, 0, stream>>>(key_,  ipw + 1 * EMB * EMB, ipb + EMB,   kbuf,
                                          L_NODES, EMB, EMB, 1.f);
        gemm_bt<<<gblk, 256, 0, stream>>>(value, ipw + 2 * EMB * EMB, ipb + 2*EMB, vbuf,
                                          L_NODES, EMB, EMB, 1.f);
        edge_attn<<<L_NODES, 512, 0, stream>>>(qbuf, kbuf, vbuf, indices + NNZ_E, qbuf);
        gemm_bt<<<gblk, 256, 0, stream>>>(qbuf, opw, opb, out, L_NODES, EMB, EMB, 1.f);
    }
}

// Round 12
// 106.712 us; speedup vs baseline: 1.5075x; 1.3217x over previous
//
#include <hip/hip_runtime.h>
#include <math.h>

#define L_NODES 16384
#define EMB 512
#define NHEAD 8
#define HDIM 64
#define DEG 16
#define NNZ_E (L_NODES * DEG)

typedef __attribute__((ext_vector_type(8))) short short8;
typedef __attribute__((ext_vector_type(4))) float f32x4;

// ---------------- fp32 -> bf16 convert (RNE) ----------------
__device__ inline short f2bs(float x) {
    union { float f; unsigned u; } c; c.f = x;
    unsigned r = (c.u + 0x7fffu + ((c.u >> 16) & 1u)) >> 16;
    return (short)r;
}

__device__ inline void cv8(const float* __restrict__ s, short* __restrict__ d, int i) {
    float4 a = reinterpret_cast<const float4*>(s)[2 * i];
    float4 b = reinterpret_cast<const float4*>(s)[2 * i + 1];
    short8 o;
    o[0] = f2bs(a.x); o[1] = f2bs(a.y); o[2] = f2bs(a.z); o[3] = f2bs(a.w);
    o[4] = f2bs(b.x); o[5] = f2bs(b.y); o[6] = f2bs(b.z); o[7] = f2bs(b.w);
    reinterpret_cast<short8*>(d)[i] = o;
}

__global__ __launch_bounds__(256) void f2bw(
    const float* __restrict__ w1, short* __restrict__ d1, int n1,
    const float* __restrict__ w2, short* __restrict__ d2, int n2) {
    const int stride = gridDim.x * blockDim.x;
    for (int i = blockIdx.x * blockDim.x + threadIdx.x; i < n1 + n2; i += stride) {
        if (i < n1) cv8(w1, d1, i); else cv8(w2, d2, i - n1);
    }
}

// bf16x8 (as short8) -> 8 floats
__device__ inline void b2f8(short8 s, float* f) {
    const unsigned* u = reinterpret_cast<const unsigned*>(&s);
#pragma unroll
    for (int j = 0; j < 4; ++j) {
        unsigned lo = u[j] << 16;
        unsigned hi = u[j] & 0xFFFF0000u;
        f[2 * j]     = __builtin_bit_cast(float, lo);
        f[2 * j + 1] = __builtin_bit_cast(float, hi);
    }
}

__device__ inline void gload16(const short* g, short* l) {
    __builtin_amdgcn_global_load_lds(
        (const __attribute__((address_space(1))) unsigned*)g,
        (__attribute__((address_space(3))) unsigned*)l, 16, 0, 0);
}

__device__ inline short8 cvt16(float4 a0, float4 a1) {
    short8 s;
    s[0] = f2bs(a0.x); s[1] = f2bs(a0.y); s[2] = f2bs(a0.z); s[3] = f2bs(a0.w);
    s[4] = f2bs(a1.x); s[5] = f2bs(a1.y); s[6] = f2bs(a1.z); s[7] = f2bs(a1.w);
    return s;
}

// 3-bit slot swizzle: phys = logical ^ x(row).
__device__ inline int swz8(int r) { return ((r >> 1) & 3) | ((r & 1) << 2); }

// ---------------- fused QKV GEMM: 128x256 tile, BK=64 ----------------
#define QBM 128
#define QBN 256
#define QBK 64

__global__ __launch_bounds__(512) void gemm_qkv(
    const float* __restrict__ q_in, const float* __restrict__ k_in,
    const float* __restrict__ v_in, const short* __restrict__ wqkv,
    const float* __restrict__ bias_all,
    short* __restrict__ qo, short* __restrict__ ko, short* __restrict__ vo)
{
    __shared__ __align__(16) short As[QBM * QBK];   // 16 KB
    __shared__ __align__(16) short Bs[QBN * QBK];   // 32 KB

    const int gid   = blockIdx.x;
    const int which = gid >> 8;
    const int inner = gid & 255;

    const float* A    = which == 0 ? q_in : (which == 1 ? k_in : v_in);
    const short* B    = wqkv + which * 262144;
    const float* bias = bias_all + which * 512;
    short*       C    = which == 0 ? qo : (which == 1 ? ko : vo);
    const float scale = which == 0 ? 0.125f : 1.0f;

    const int t    = threadIdx.x;
    const int wid  = t >> 6;
    const int lane = t & 63;

    const int wg = (inner & 7) * 32 + (inner >> 3);
    const int bx = wg & 1;
    const int by = wg >> 1;
    const int row0 = by * QBM;
    const int col0 = bx * QBN;

    const int ar  = t >> 2;
    const int q2  = (t & 3) << 1;
    const int xa  = swz8(ar);
    const int la0 = q2 ^ xa;
    const int la1 = (q2 + 1) ^ xa;
    const float* Aga = A + (size_t)(row0 + ar) * 512;
    short* awp0 = &As[ar * QBK + q2 * 8];
    short* awp1 = awp0 + 8;

    const int brw = t >> 3;
    const int bp  = t & 7;
    const int xb  = swz8(brw & 7);
    const short* Bgb = B + (size_t)(col0 + brw) * 512 + (bp ^ xb) * 8;
    short* Bld = &Bs[(wid * 8) * QBK];

    const int wr = wid >> 2;
    const int wc = wid & 3;

    f32x4 acc[4][4] = {};

    for (int k0 = 0; k0 < 512; k0 += QBK) {
#pragma unroll
        for (int j = 0; j < 4; ++j)
            gload16(Bgb + (size_t)j * 64 * 512 + k0, Bld + j * 64 * QBK);
        {
            const float* ap0 = Aga + la0 * 8 + k0;
            const float* ap1 = Aga + la1 * 8 + k0;
            float4 a0 = *reinterpret_cast<const float4*>(ap0);
            float4 a1 = *reinterpret_cast<const float4*>(ap0 + 4);
            float4 a2 = *reinterpret_cast<const float4*>(ap1);
            float4 a3 = *reinterpret_cast<const float4*>(ap1 + 4);
            *reinterpret_cast<short8*>(awp0) = cvt16(a0, a1);
            *reinterpret_cast<short8*>(awp1) = cvt16(a2, a3);
        }
        __syncthreads();

#pragma unroll
        for (int kk = 0; kk < 2; ++kk) {
            short8 af[4], bf[4];
#pragma unroll
            for (int i = 0; i < 4; ++i) {
                const int r  = wr * 64 + i * 16 + (lane & 15);
                const int sl = (kk * 4 + (lane >> 4)) ^ swz8(r);
                af[i] = *reinterpret_cast<const short8*>(&As[r * QBK + sl * 8]);
            }
#pragma unroll
            for (int j = 0; j < 4; ++j) {
                const int r  = wc * 64 + j * 16 + (lane & 15);
                const int sl = (kk * 4 + (lane >> 4)) ^ swz8(r);
                bf[j] = *reinterpret_cast<const short8*>(&Bs[r * QBK + sl * 8]);
            }
#pragma unroll
            for (int i = 0; i < 4; ++i)
#pragma unroll
                for (int j = 0; j < 4; ++j)
                    acc[i][j] = __builtin_amdgcn_mfma_f32_16x16x32_bf16(
                        af[i], bf[j], acc[i][j], 0, 0, 0);
        }
        __syncthreads();
    }

    float bv[4];
#pragma unroll
    for (int j = 0; j < 4; ++j) bv[j] = bias[col0 + wc * 64 + j * 16 + (lane & 15)];
#pragma unroll
    for (int i = 0; i < 4; ++i) {
        const int rbase = row0 + wr * 64 + i * 16 + (lane >> 4) * 4;
#pragma unroll
        for (int j = 0; j < 4; ++j) {
            const int col = col0 + wc * 64 + j * 16 + (lane & 15);
#pragma unroll
            for (int rg = 0; rg < 4; ++rg)
                C[(size_t)(rbase + rg) * 512 + col] =
                    f2bs((acc[i][j][rg] + bv[j]) * scale);
        }
    }
}

// ---------------- out-proj GEMM: 128x128, BK=64 ----------------
#define OBK 64

__global__ __launch_bounds__(256) void gemm_out(
    const short* __restrict__ A, const short* __restrict__ B,
    const float* __restrict__ bias, float* __restrict__ C)
{
    __shared__ __align__(16) short As[128 * OBK];
    __shared__ __align__(16) short Bs[128 * OBK];

    const int t    = threadIdx.x;
    const int wid  = t >> 6;
    const int lane = t & 63;

    const int cpx = gridDim.x >> 3;
    const int bid = blockIdx.x;
    const int wg  = (bid & 7) * cpx + (bid >> 3);
    const int bx  = wg & 3;
    const int by  = wg >> 2;
    const int row0 = by * 128;
    const int col0 = bx * 128;

    const int rw = t >> 3;
    const int p  = t & 7;
    const int xs = swz8(rw & 7);
    const short* AgS = A + (size_t)(row0 + rw) * 512 + (p ^ xs) * 8;
    const short* BgS = B + (size_t)(col0 + rw) * 512 + (p ^ xs) * 8;
    short* Ald = &As[(wid * 8) * OBK];
    short* Bld = &Bs[(wid * 8) * OBK];

    const int wr = wid >> 1, wc = wid & 1;

    f32x4 acc[4][4] = {};

    for (int k0 = 0; k0 < 512; k0 += OBK) {
#pragma unroll
        for (int j = 0; j < 4; ++j) {
            gload16(AgS + (size_t)j * 32 * 512 + k0, Ald + j * 32 * OBK);
            gload16(BgS + (size_t)j * 32 * 512 + k0, Bld + j * 32 * OBK);
        }
        __syncthreads();

#pragma unroll
        for (int kk = 0; kk < 2; ++kk) {
            short8 af[4], bf[4];
#pragma unroll
            for (int i = 0; i < 4; ++i) {
                const int r  = wr * 64 + i * 16 + (lane & 15);
                const int sl = (kk * 4 + (lane >> 4)) ^ swz8(r);
                af[i] = *reinterpret_cast<const short8*>(&As[r * OBK + sl * 8]);
            }
#pragma unroll
            for (int j = 0; j < 4; ++j) {
                const int r  = wc * 64 + j * 16 + (lane & 15);
                const int sl = (kk * 4 + (lane >> 4)) ^ swz8(r);
                bf[j] = *reinterpret_cast<const short8*>(&Bs[r * OBK + sl * 8]);
            }
#pragma unroll
            for (int i = 0; i < 4; ++i)
#pragma unroll
                for (int j = 0; j < 4; ++j)
                    acc[i][j] = __builtin_amdgcn_mfma_f32_16x16x32_bf16(
                        af[i], bf[j], acc[i][j], 0, 0, 0);
        }
        __syncthreads();
    }

    float bv[4];
#pragma unroll
    for (int j = 0; j < 4; ++j) bv[j] = bias[col0 + wc * 64 + j * 16 + (lane & 15)];
#pragma unroll
    for (int i = 0; i < 4; ++i) {
        const int rbase = row0 + wr * 64 + i * 16 + (lane >> 4) * 4;
#pragma unroll
        for (int j = 0; j < 4; ++j) {
            const int col = col0 + wc * 64 + j * 16 + (lane & 15);
#pragma unroll
            for (int rg = 0; rg < 4; ++rg)
                C[(size_t)(rbase + rg) * 512 + col] = acc[i][j][rg] + bv[j];
        }
    }
}

// ---------------- edge softmax/aggregate, v5: head->XCD affinity ----------------
__device__ inline float edge_core(const float* qf, short8 k0, short8 k1,
                                  short8 v0, short8 v1, int lane) {
    float kf0[8], kf1[8];
    b2f8(k0, kf0); b2f8(k1, kf1);
    float p0 = 0.f, p1 = 0.f;
#pragma unroll
    for (int j = 0; j < 8; ++j) { p0 += qf[j] * kf0[j]; p1 += qf[j] * kf1[j]; }

    const bool b0 = (lane & 1) != 0;
    float x = b0 ? p0 : p1;
    float r = __shfl_xor(x, 1, 64);
    float s = (b0 ? p1 : p0) + r;
    s += __shfl_xor(s, 2, 64);
    s += __shfl_xor(s, 4, 64);

    float m = s;
    m = fmaxf(m, __shfl_xor(m, 1, 64));
    m = fmaxf(m, __shfl_xor(m, 8, 64));
    m = fmaxf(m, __shfl_xor(m, 16, 64));
    m = fmaxf(m, __shfl_xor(m, 32, 64));
    float w = expf(s - m);
    float den = w;
    den += __shfl_xor(den, 1, 64);
    den += __shfl_xor(den, 8, 64);
    den += __shfl_xor(den, 16, 64);
    den += __shfl_xor(den, 32, 64);
    w *= (1.0f / den);

    const int srcb = lane & 56;
    const float w0 = __shfl(w, srcb, 64);
    const float w1 = __shfl(w, srcb | 1, 64);

    float vf0[8], vf1[8], of[8];
    b2f8(v0, vf0); b2f8(v1, vf1);
#pragma unroll
    for (int j = 0; j < 8; ++j) of[j] = w0 * vf0[j] + w1 * vf1[j];

    const bool b3 = (lane & 8) != 0;
    float o4[4];
#pragma unroll
    for (int j = 0; j < 4; ++j) {
        float send = b3 ? of[j] : of[4 + j];
        float recv = __shfl_xor(send, 8, 64);
        o4[j] = (b3 ? of[4 + j] : of[j]) + recv;
    }
    const bool b4 = (lane & 16) != 0;
    float z0 = __shfl_xor(b4 ? o4[0] : o4[2], 16, 64);
    float z1 = __shfl_xor(b4 ? o4[1] : o4[3], 16, 64);
    float t0 = (b4 ? o4[2] : o4[0]) + z0;
    float t1 = (b4 ? o4[3] : o4[1]) + z1;
    const bool b5 = (lane & 32) != 0;
    float zz = __shfl_xor(b5 ? t0 : t1, 32, 64);
    return (b5 ? t1 : t0) + zz;
}

// Block = (head, 16-node group): head = blockIdx&7 so round-robin dispatch pins
// head h to XCD h; each XCD's K/V working set = 2+2 MB = its 4 MB L2.
// 8 waves x 2 nodes, all on the SAME head. Mapping is perf-only.
__global__ __launch_bounds__(512) void edge_attn5(
    const short* __restrict__ qm, const short* __restrict__ km,
    const short* __restrict__ vm, const int* __restrict__ colidx,
    short* __restrict__ outb)
{
    const int h    = blockIdx.x & 7;
    const int grp  = blockIdx.x >> 3;
    const int wid  = threadIdx.x >> 6;
    const int lane = threadIdx.x & 63;
    const int i0   = grp * 16 + wid * 2;
    const int c    = lane & 7;
    const int g    = lane >> 3;

    int creg = 0;
    if (lane < 2 * DEG) creg = colidx[i0 * DEG + lane];
    const int ca0 = __shfl(creg, g, 64);
    const int ca1 = __shfl(creg, g + 8, 64);
    const int cb0 = __shfl(creg, 16 + g, 64);
    const int cb1 = __shfl(creg, 16 + g + 8, 64);

    const size_t dof = (size_t)h * HDIM + 8 * c;
    short8 qA  = *reinterpret_cast<const short8*>(&qm[(size_t)i0 * EMB + dof]);
    short8 qB  = *reinterpret_cast<const short8*>(&qm[(size_t)(i0 + 1) * EMB + dof]);
    short8 kA0 = *reinterpret_cast<const short8*>(&km[(size_t)ca0 * EMB + dof]);
    short8 kA1 = *reinterpret_cast<const short8*>(&km[(size_t)ca1 * EMB + dof]);
    short8 kB0 = *reinterpret_cast<const short8*>(&km[(size_t)cb0 * EMB + dof]);
    short8 kB1 = *reinterpret_cast<const short8*>(&km[(size_t)cb1 * EMB + dof]);
    short8 vA0 = *reinterpret_cast<const short8*>(&vm[(size_t)ca0 * EMB + dof]);
    short8 vA1 = *reinterpret_cast<const short8*>(&vm[(size_t)ca1 * EMB + dof]);
    short8 vB0 = *reinterpret_cast<const short8*>(&vm[(size_t)cb0 * EMB + dof]);
    short8 vB1 = *reinterpret_cast<const short8*>(&vm[(size_t)cb1 * EMB + dof]);

    float qfA[8], qfB[8];
    b2f8(qA, qfA); b2f8(qB, qfB);

    const float oA = edge_core(qfA, kA0, kA1, vA0, vA1, lane);
    const float oB = edge_core(qfB, kB0, kB1, vB0, vB1, lane);

    const int d = 8 * c + ((lane & 8) ? 4 : 0) + ((lane & 16) ? 2 : 0)
                        + ((lane & 32) ? 1 : 0);
    outb[(size_t)i0 * EMB + h * HDIM + d]       = f2bs(oA);
    outb[(size_t)(i0 + 1) * EMB + h * HDIM + d] = f2bs(oB);
}

// ---------------- fp32 fallback path ----------------
#define TILE 64
#define BKK 16
#define PAD_LD 68

__global__ __launch_bounds__(256) void gemm_bt(
    const float* __restrict__ A, const float* __restrict__ W,
    const float* __restrict__ bias, float* __restrict__ C,
    int M, int K, int N, float scale)
{
    __shared__ float Asm[BKK][PAD_LD];
    __shared__ float Bsm[BKK][PAD_LD];
    const int t  = threadIdx.x;
    const int tx = t & 15;
    const int ty = t >> 4;
    const int row0 = blockIdx.y * TILE;
    const int col0 = blockIdx.x * TILE;
    const int lr = t >> 2;
    const int lk = (t & 3) << 2;
    const float* Aptr = A + (size_t)(row0 + lr) * K + lk;
    const float* Wptr = W + (size_t)(col0 + lr) * K + lk;
    float acc[4][4] = {};
    for (int k0 = 0; k0 < K; k0 += BKK) {
        float4 a4 = *reinterpret_cast<const float4*>(Aptr + k0);
        float4 b4 = *reinterpret_cast<const float4*>(Wptr + k0);
        Asm[lk + 0][lr] = a4.x; Asm[lk + 1][lr] = a4.y;
        Asm[lk + 2][lr] = a4.z; Asm[lk + 3][lr] = a4.w;
        Bsm[lk + 0][lr] = b4.x; Bsm[lk + 1][lr] = b4.y;
        Bsm[lk + 2][lr] = b4.z; Bsm[lk + 3][lr] = b4.w;
        __syncthreads();
#pragma unroll
        for (int kk = 0; kk < BKK; ++kk) {
            float a[4], b[4];
#pragma unroll
            for (int i2 = 0; i2 < 4; ++i2) a[i2] = Asm[kk][ty * 4 + i2];
#pragma unroll
            for (int j2 = 0; j2 < 4; ++j2) b[j2] = Bsm[kk][tx * 4 + j2];
#pragma unroll
            for (int i2 = 0; i2 < 4; ++i2)
#pragma unroll
                for (int j2 = 0; j2 < 4; ++j2)
                    acc[i2][j2] += a[i2] * b[j2];
        }
        __syncthreads();
    }
#pragma unroll
    for (int i2 = 0; i2 < 4; ++i2) {
        const int r = row0 + ty * 4 + i2;
        float4 o;
        o.x = (acc[i2][0] + bias[col0 + tx * 4 + 0]) * scale;
        o.y = (acc[i2][1] + bias[col0 + tx * 4 + 1]) * scale;
        o.z = (acc[i2][2] + bias[col0 + tx * 4 + 2]) * scale;
        o.w = (acc[i2][3] + bias[col0 + tx * 4 + 3]) * scale;
        *reinterpret_cast<float4*>(&C[(size_t)r * N + col0 + tx * 4]) = o;
    }
}

__global__ __launch_bounds__(512) void edge_attn(
    const float* q, const float* __restrict__ kmat, const float* __restrict__ vmat,
    const int* __restrict__ colidx, float* out)
{
    const int i    = blockIdx.x;
    const int h    = threadIdx.x >> 6;
    const int lane = threadIdx.x & 63;
    const size_t base = (size_t)i * EMB + h * HDIM + lane;

    const float qd = q[base];
    int creg = 0;
    if (lane < DEG) creg = colidx[i * DEG + lane];

    float kr[DEG], vr[DEG];
#pragma unroll
    for (int e = 0; e < DEG; ++e) {
        const int ce = __shfl(creg, e, 64);
        const size_t cb = (size_t)ce * EMB + h * HDIM + lane;
        kr[e] = kmat[cb];
        vr[e] = vmat[cb];
    }
    float s[DEG];
#pragma unroll
    for (int e = 0; e < DEG; ++e) {
        float p = qd * kr[e];
#pragma unroll
        for (int off = 32; off; off >>= 1) p += __shfl_xor(p, off, 64);
        s[e] = p;
    }
    float m = s[0];
#pragma unroll
    for (int e = 1; e < DEG; ++e) m = fmaxf(m, s[e]);
    float denom = 0.f;
#pragma unroll
    for (int e = 0; e < DEG; ++e) { s[e] = expf(s[e] - m); denom += s[e]; }
    const float inv = 1.f / denom;
    float o = 0.f;
#pragma unroll
    for (int e = 0; e < DEG; ++e) o += s[e] * vr[e];
    out[base] = o * inv;
}

extern "C" void kernel_launch(void* const* d_in, const int* in_sizes, int n_in,
                              void* d_out, int out_size, void* d_ws, size_t ws_size,
                              hipStream_t stream) {
    const float* query   = (const float*)d_in[0];
    const float* key_    = (const float*)d_in[1];
    const float* value   = (const float*)d_in[2];
    const int*   indices = (const int*)  d_in[3];
    const float* ipw     = (const float*)d_in[4];
    const float* ipb     = (const float*)d_in[5];
    const float* opw     = (const float*)d_in[6];
    const float* opb     = (const float*)d_in[7];
    float* out = (float*)d_out;

    const size_t NEED = 70000000;  // shorts: wqkv+wo+qo+ko+vo+ab = 69.2 MB

    if (ws_size >= NEED) {
        short* wqkv = (short*)d_ws;          // 786432
        short* wo   = wqkv + 786432;         // 262144
        short* qo   = wo + 262144;           // 8388608 each
        short* ko   = qo + 8388608;
        short* vo   = ko + 8388608;
        short* ab   = vo + 8388608;          // attn out bf16

        f2bw<<<512, 256, 0, stream>>>(ipw, wqkv, 98304, opw, wo, 32768);
        gemm_qkv<<<768, 512, 0, stream>>>(query, key_, value, wqkv, ipb,
                                          qo, ko, vo);
        edge_attn5<<<L_NODES / 2, 512, 0, stream>>>(qo, ko, vo,
                                                    indices + NNZ_E, ab);
        gemm_out<<<512, 256, 0, stream>>>(ab, wo, opb, out);
    } else {
        float* qbuf = (float*)d_ws;
        float* kbuf = qbuf + (size_t)L_NODES * EMB;
        float* vbuf = kbuf + (size_t)L_NODES * EMB;
        const dim3 gblk(EMB / TILE, L_NODES / TILE);
        const float scaling = 0.125f;
        gemm_bt<<<gblk, 256, 0, stream>>>(query, ipw,                 ipb,         qbuf,
                                          L_NODES, EMB, EMB, scaling);
        gemm_bt<<<gblk, 256, 0, stream>>>(key_,  ipw + 1 * EMB * EMB, ipb + EMB,   kbuf,
                                          L_NODES, EMB, EMB, 1.f);
        gemm_bt<<<gblk, 256, 0, stream>>>(value, ipw + 2 * EMB * EMB, ipb + 2*EMB, vbuf,
                                          L_NODES, EMB, EMB, 1.f);
        edge_attn<<<L_NODES, 512, 0, stream>>>(qbuf, kbuf, vbuf, indices + NNZ_E, qbuf);
        gemm_bt<<<gblk, 256, 0, stream>>>(qbuf, opw, opb, out, L_NODES, EMB, EMB, 1.f);
    }
}

// Round 14
// 106.449 us; speedup vs baseline: 1.5112x; 1.0025x over previous
//
#include <hip/hip_runtime.h>
#include <math.h>

#define L_NODES 16384
#define EMB 512
#define NHEAD 8
#define HDIM 64
#define DEG 16
#define NNZ_E (L_NODES * DEG)

typedef __attribute__((ext_vector_type(8))) short short8;
typedef __attribute__((ext_vector_type(4))) float f32x4;

// ---------------- fp32 -> bf16 convert (RNE) ----------------
__device__ inline short f2bs(float x) {
    union { float f; unsigned u; } c; c.f = x;
    unsigned r = (c.u + 0x7fffu + ((c.u >> 16) & 1u)) >> 16;
    return (short)r;
}

__device__ inline void cv8(const float* __restrict__ s, short* __restrict__ d, int i) {
    float4 a = reinterpret_cast<const float4*>(s)[2 * i];
    float4 b = reinterpret_cast<const float4*>(s)[2 * i + 1];
    short8 o;
    o[0] = f2bs(a.x); o[1] = f2bs(a.y); o[2] = f2bs(a.z); o[3] = f2bs(a.w);
    o[4] = f2bs(b.x); o[5] = f2bs(b.y); o[6] = f2bs(b.z); o[7] = f2bs(b.w);
    reinterpret_cast<short8*>(d)[i] = o;
}

__global__ __launch_bounds__(256) void f2bw(
    const float* __restrict__ w1, short* __restrict__ d1, int n1,
    const float* __restrict__ w2, short* __restrict__ d2, int n2) {
    const int stride = gridDim.x * blockDim.x;
    for (int i = blockIdx.x * blockDim.x + threadIdx.x; i < n1 + n2; i += stride) {
        if (i < n1) cv8(w1, d1, i); else cv8(w2, d2, i - n1);
    }
}

// bf16x8 (as short8) -> 8 floats
__device__ inline void b2f8(short8 s, float* f) {
    const unsigned* u = reinterpret_cast<const unsigned*>(&s);
#pragma unroll
    for (int j = 0; j < 4; ++j) {
        unsigned lo = u[j] << 16;
        unsigned hi = u[j] & 0xFFFF0000u;
        f[2 * j]     = __builtin_bit_cast(float, lo);
        f[2 * j + 1] = __builtin_bit_cast(float, hi);
    }
}

__device__ inline void gload16(const short* g, short* l) {
    __builtin_amdgcn_global_load_lds(
        (const __attribute__((address_space(1))) unsigned*)g,
        (__attribute__((address_space(3))) unsigned*)l, 16, 0, 0);
}

__device__ inline short8 cvt16(float4 a0, float4 a1) {
    short8 s;
    s[0] = f2bs(a0.x); s[1] = f2bs(a0.y); s[2] = f2bs(a0.z); s[3] = f2bs(a0.w);
    s[4] = f2bs(a1.x); s[5] = f2bs(a1.y); s[6] = f2bs(a1.z); s[7] = f2bs(a1.w);
    return s;
}

// 3-bit slot swizzle: phys = logical ^ swz8(row).
__device__ inline int swz8(int r) { return ((r >> 1) & 3) | ((r & 1) << 2); }

// ---------------- fused QKV GEMM: 128x256 tile, BK=64 ----------------
// At BK=64 the LDS row stride is 128B == 32 banks, so bank = f(slot) only.
// WRITE-side fix (round 13): physical write slots p0 = q2 ^ swz8(row), p1 =
// p0^1 -> 8 distinct bank positions per 32-lane phase (was 4 -> 8-way
// conflict, 3.9M SQ_LDS_BANK_CONFLICT). Source becomes the contiguous
// logical pair q2,q2+1 (64B per thread). Data placement bit-identical.
#define QBM 128
#define QBN 256
#define QBK 64

__global__ __launch_bounds__(512) void gemm_qkv(
    const float* __restrict__ q_in, const float* __restrict__ k_in,
    const float* __restrict__ v_in, const short* __restrict__ wqkv,
    const float* __restrict__ bias_all,
    short* __restrict__ qo, short* __restrict__ ko, short* __restrict__ vo)
{
    __shared__ __align__(16) short As[QBM * QBK];   // 16 KB
    __shared__ __align__(16) short Bs[QBN * QBK];   // 32 KB

    const int gid   = blockIdx.x;
    const int which = gid >> 8;
    const int inner = gid & 255;

    const float* A    = which == 0 ? q_in : (which == 1 ? k_in : v_in);
    const short* B    = wqkv + which * 262144;
    const float* bias = bias_all + which * 512;
    short*       C    = which == 0 ? qo : (which == 1 ? ko : vo);
    const float scale = which == 0 ? 0.125f : 1.0f;

    const int t    = threadIdx.x;
    const int wid  = t >> 6;
    const int lane = t & 63;

    const int wg = (inner & 7) * 32 + (inner >> 3);
    const int bx = wg & 1;
    const int by = wg >> 1;
    const int row0 = by * QBM;
    const int col0 = bx * QBN;

    // A staging: row ar = t>>2, logical slot-pair q2 = (t&3)*2 (contiguous
    // 16 floats); physical slots p0 = q2^swz8(ar), p1 = p0^1.
    const int ar  = t >> 2;
    const int q2  = (t & 3) << 1;
    const int xa  = swz8(ar);
    const int p0  = q2 ^ xa;
    const int p1  = p0 ^ 1;
    const float* Aga = A + (size_t)(row0 + ar) * 512 + q2 * 8;
    short* awp0 = &As[ar * QBK + p0 * 8];
    short* awp1 = &As[ar * QBK + p1 * 8];

    // B staging via global_load_lds: source-address swizzle, linear LDS dest.
    const int brw = t >> 3;
    const int bp  = t & 7;
    const int xb  = swz8(brw & 7);
    const short* Bgb = B + (size_t)(col0 + brw) * 512 + (bp ^ xb) * 8;
    short* Bld = &Bs[(wid * 8) * QBK];

    const int wr = wid >> 2;
    const int wc = wid & 3;

    f32x4 acc[4][4] = {};

    for (int k0 = 0; k0 < 512; k0 += QBK) {
#pragma unroll
        for (int j = 0; j < 4; ++j)
            gload16(Bgb + (size_t)j * 64 * 512 + k0, Bld + j * 64 * QBK);
        {
            const float* ap = Aga + k0;
            float4 a0 = *reinterpret_cast<const float4*>(ap);
            float4 a1 = *reinterpret_cast<const float4*>(ap + 4);
            float4 a2 = *reinterpret_cast<const float4*>(ap + 8);
            float4 a3 = *reinterpret_cast<const float4*>(ap + 12);
            *reinterpret_cast<short8*>(awp0) = cvt16(a0, a1);   // logical q2
            *reinterpret_cast<short8*>(awp1) = cvt16(a2, a3);   // logical q2+1
        }
        __syncthreads();

#pragma unroll
        for (int kk = 0; kk < 2; ++kk) {
            short8 af[4], bf[4];
#pragma unroll
            for (int i = 0; i < 4; ++i) {
                const int r  = wr * 64 + i * 16 + (lane & 15);
                const int sl = (kk * 4 + (lane >> 4)) ^ swz8(r);
                af[i] = *reinterpret_cast<const short8*>(&As[r * QBK + sl * 8]);
            }
#pragma unroll
            for (int j = 0; j < 4; ++j) {
                const int r  = wc * 64 + j * 16 + (lane & 15);
                const int sl = (kk * 4 + (lane >> 4)) ^ swz8(r);
                bf[j] = *reinterpret_cast<const short8*>(&Bs[r * QBK + sl * 8]);
            }
#pragma unroll
            for (int i = 0; i < 4; ++i)
#pragma unroll
                for (int j = 0; j < 4; ++j)
                    acc[i][j] = __builtin_amdgcn_mfma_f32_16x16x32_bf16(
                        af[i], bf[j], acc[i][j], 0, 0, 0);
        }
        __syncthreads();
    }

    float bv[4];
#pragma unroll
    for (int j = 0; j < 4; ++j) bv[j] = bias[col0 + wc * 64 + j * 16 + (lane & 15)];
#pragma unroll
    for (int i = 0; i < 4; ++i) {
        const int rbase = row0 + wr * 64 + i * 16 + (lane >> 4) * 4;
#pragma unroll
        for (int j = 0; j < 4; ++j) {
            const int col = col0 + wc * 64 + j * 16 + (lane & 15);
#pragma unroll
            for (int rg = 0; rg < 4; ++rg)
                C[(size_t)(rbase + rg) * 512 + col] =
                    f2bs((acc[i][j][rg] + bv[j]) * scale);
        }
    }
}

// ---------------- out-proj GEMM: 128x128, BK=64, both operands gload_lds ----------------
#define OBK 64

__global__ __launch_bounds__(256) void gemm_out(
    const short* __restrict__ A, const short* __restrict__ B,
    const float* __restrict__ bias, float* __restrict__ C)
{
    __shared__ __align__(16) short As[128 * OBK];
    __shared__ __align__(16) short Bs[128 * OBK];

    const int t    = threadIdx.x;
    const int wid  = t >> 6;
    const int lane = t & 63;

    const int cpx = gridDim.x >> 3;
    const int bid = blockIdx.x;
    const int wg  = (bid & 7) * cpx + (bid >> 3);
    const int bx  = wg & 3;
    const int by  = wg >> 2;
    const int row0 = by * 128;
    const int col0 = bx * 128;

    const int rw = t >> 3;
    const int p  = t & 7;
    const int xs = swz8(rw & 7);
    const short* AgS = A + (size_t)(row0 + rw) * 512 + (p ^ xs) * 8;
    const short* BgS = B + (size_t)(col0 + rw) * 512 + (p ^ xs) * 8;
    short* Ald = &As[(wid * 8) * OBK];
    short* Bld = &Bs[(wid * 8) * OBK];

    const int wr = wid >> 1, wc = wid & 1;

    f32x4 acc[4][4] = {};

    for (int k0 = 0; k0 < 512; k0 += OBK) {
#pragma unroll
        for (int j = 0; j < 4; ++j) {
            gload16(AgS + (size_t)j * 32 * 512 + k0, Ald + j * 32 * OBK);
            gload16(BgS + (size_t)j * 32 * 512 + k0, Bld + j * 32 * OBK);
        }
        __syncthreads();

#pragma unroll
        for (int kk = 0; kk < 2; ++kk) {
            short8 af[4], bf[4];
#pragma unroll
            for (int i = 0; i < 4; ++i) {
                const int r  = wr * 64 + i * 16 + (lane & 15);
                const int sl = (kk * 4 + (lane >> 4)) ^ swz8(r);
                af[i] = *reinterpret_cast<const short8*>(&As[r * OBK + sl * 8]);
            }
#pragma unroll
            for (int j = 0; j < 4; ++j) {
                const int r  = wc * 64 + j * 16 + (lane & 15);
                const int sl = (kk * 4 + (lane >> 4)) ^ swz8(r);
                bf[j] = *reinterpret_cast<const short8*>(&Bs[r * OBK + sl * 8]);
            }
#pragma unroll
            for (int i = 0; i < 4; ++i)
#pragma unroll
                for (int j = 0; j < 4; ++j)
                    acc[i][j] = __builtin_amdgcn_mfma_f32_16x16x32_bf16(
                        af[i], bf[j], acc[i][j], 0, 0, 0);
        }
        __syncthreads();
    }

    float bv[4];
#pragma unroll
    for (int j = 0; j < 4; ++j) bv[j] = bias[col0 + wc * 64 + j * 16 + (lane & 15)];
#pragma unroll
    for (int i = 0; i < 4; ++i) {
        const int rbase = row0 + wr * 64 + i * 16 + (lane >> 4) * 4;
#pragma unroll
        for (int j = 0; j < 4; ++j) {
            const int col = col0 + wc * 64 + j * 16 + (lane & 15);
#pragma unroll
            for (int rg = 0; rg < 4; ++rg)
                C[(size_t)(rbase + rg) * 512 + col] = acc[i][j][rg] + bv[j];
        }
    }
}

// ---------------- edge softmax/aggregate, v5: head->XCD affinity ----------------
__device__ inline float edge_core(const float* qf, short8 k0, short8 k1,
                                  short8 v0, short8 v1, int lane) {
    float kf0[8], kf1[8];
    b2f8(k0, kf0); b2f8(k1, kf1);
    float p0 = 0.f, p1 = 0.f;
#pragma unroll
    for (int j = 0; j < 8; ++j) { p0 += qf[j] * kf0[j]; p1 += qf[j] * kf1[j]; }

    const bool b0 = (lane & 1) != 0;
    float x = b0 ? p0 : p1;
    float r = __shfl_xor(x, 1, 64);
    float s = (b0 ? p1 : p0) + r;
    s += __shfl_xor(s, 2, 64);
    s += __shfl_xor(s, 4, 64);

    float m = s;
    m = fmaxf(m, __shfl_xor(m, 1, 64));
    m = fmaxf(m, __shfl_xor(m, 8, 64));
    m = fmaxf(m, __shfl_xor(m, 16, 64));
    m = fmaxf(m, __shfl_xor(m, 32, 64));
    float w = expf(s - m);
    float den = w;
    den += __shfl_xor(den, 1, 64);
    den += __shfl_xor(den, 8, 64);
    den += __shfl_xor(den, 16, 64);
    den += __shfl_xor(den, 32, 64);
    w *= (1.0f / den);

    const int srcb = lane & 56;
    const float w0 = __shfl(w, srcb, 64);
    const float w1 = __shfl(w, srcb | 1, 64);

    float vf0[8], vf1[8], of[8];
    b2f8(v0, vf0); b2f8(v1, vf1);
#pragma unroll
    for (int j = 0; j < 8; ++j) of[j] = w0 * vf0[j] + w1 * vf1[j];

    const bool b3 = (lane & 8) != 0;
    float o4[4];
#pragma unroll
    for (int j = 0; j < 4; ++j) {
        float send = b3 ? of[j] : of[4 + j];
        float recv = __shfl_xor(send, 8, 64);
        o4[j] = (b3 ? of[4 + j] : of[j]) + recv;
    }
    const bool b4 = (lane & 16) != 0;
    float z0 = __shfl_xor(b4 ? o4[0] : o4[2], 16, 64);
    float z1 = __shfl_xor(b4 ? o4[1] : o4[3], 16, 64);
    float t0 = (b4 ? o4[2] : o4[0]) + z0;
    float t1 = (b4 ? o4[3] : o4[1]) + z1;
    const bool b5 = (lane & 32) != 0;
    float zz = __shfl_xor(b5 ? t0 : t1, 32, 64);
    return (b5 ? t1 : t0) + zz;
}

// Block = (head, 16-node group): head = blockIdx&7 -> round-robin dispatch
// pins head h to XCD h; each XCD's K/V working set = 4 MB = its L2.
__global__ __launch_bounds__(512) void edge_attn5(
    const short* __restrict__ qm, const short* __restrict__ km,
    const short* __restrict__ vm, const int* __restrict__ colidx,
    short* __restrict__ outb)
{
    const int h    = blockIdx.x & 7;
    const int grp  = blockIdx.x >> 3;
    const int wid  = threadIdx.x >> 6;
    const int lane = threadIdx.x & 63;
    const int i0   = grp * 16 + wid * 2;
    const int c    = lane & 7;
    const int g    = lane >> 3;

    int creg = 0;
    if (lane < 2 * DEG) creg = colidx[i0 * DEG + lane];
    const int ca0 = __shfl(creg, g, 64);
    const int ca1 = __shfl(creg, g + 8, 64);
    const int cb0 = __shfl(creg, 16 + g, 64);
    const int cb1 = __shfl(creg, 16 + g + 8, 64);

    const size_t dof = (size_t)h * HDIM + 8 * c;
    short8 qA  = *reinterpret_cast<const short8*>(&qm[(size_t)i0 * EMB + dof]);
    short8 qB  = *reinterpret_cast<const short8*>(&qm[(size_t)(i0 + 1) * EMB + dof]);
    short8 kA0 = *reinterpret_cast<const short8*>(&km[(size_t)ca0 * EMB + dof]);
    short8 kA1 = *reinterpret_cast<const short8*>(&km[(size_t)ca1 * EMB + dof]);
    short8 kB0 = *reinterpret_cast<const short8*>(&km[(size_t)cb0 * EMB + dof]);
    short8 kB1 = *reinterpret_cast<const short8*>(&km[(size_t)cb1 * EMB + dof]);
    short8 vA0 = *reinterpret_cast<const short8*>(&vm[(size_t)ca0 * EMB + dof]);
    short8 vA1 = *reinterpret_cast<const short8*>(&vm[(size_t)ca1 * EMB + dof]);
    short8 vB0 = *reinterpret_cast<const short8*>(&vm[(size_t)cb0 * EMB + dof]);
    short8 vB1 = *reinterpret_cast<const short8*>(&vm[(size_t)cb1 * EMB + dof]);

    float qfA[8], qfB[8];
    b2f8(qA, qfA); b2f8(qB, qfB);

    const float oA = edge_core(qfA, kA0, kA1, vA0, vA1, lane);
    const float oB = edge_core(qfB, kB0, kB1, vB0, vB1, lane);

    const int d = 8 * c + ((lane & 8) ? 4 : 0) + ((lane & 16) ? 2 : 0)
                        + ((lane & 32) ? 1 : 0);
    outb[(size_t)i0 * EMB + h * HDIM + d]       = f2bs(oA);
    outb[(size_t)(i0 + 1) * EMB + h * HDIM + d] = f2bs(oB);
}

// ---------------- fp32 fallback path ----------------
#define TILE 64
#define BKK 16
#define PAD_LD 68

__global__ __launch_bounds__(256) void gemm_bt(
    const float* __restrict__ A, const float* __restrict__ W,
    const float* __restrict__ bias, float* __restrict__ C,
    int M, int K, int N, float scale)
{
    __shared__ float Asm[BKK][PAD_LD];
    __shared__ float Bsm[BKK][PAD_LD];
    const int t  = threadIdx.x;
    const int tx = t & 15;
    const int ty = t >> 4;
    const int row0 = blockIdx.y * TILE;
    const int col0 = blockIdx.x * TILE;
    const int lr = t >> 2;
    const int lk = (t & 3) << 2;
    const float* Aptr = A + (size_t)(row0 + lr) * K + lk;
    const float* Wptr = W + (size_t)(col0 + lr) * K + lk;
    float acc[4][4] = {};
    for (int k0 = 0; k0 < K; k0 += BKK) {
        float4 a4 = *reinterpret_cast<const float4*>(Aptr + k0);
        float4 b4 = *reinterpret_cast<const float4*>(Wptr + k0);
        Asm[lk + 0][lr] = a4.x; Asm[lk + 1][lr] = a4.y;
        Asm[lk + 2][lr] = a4.z; Asm[lk + 3][lr] = a4.w;
        Bsm[lk + 0][lr] = b4.x; Bsm[lk + 1][lr] = b4.y;
        Bsm[lk + 2][lr] = b4.z; Bsm[lk + 3][lr] = b4.w;
        __syncthreads();
#pragma unroll
        for (int kk = 0; kk < BKK; ++kk) {
            float a[4], b[4];
#pragma unroll
            for (int i2 = 0; i2 < 4; ++i2) a[i2] = Asm[kk][ty * 4 + i2];
#pragma unroll
            for (int j2 = 0; j2 < 4; ++j2) b[j2] = Bsm[kk][tx * 4 + j2];
#pragma unroll
            for (int i2 = 0; i2 < 4; ++i2)
#pragma unroll
                for (int j2 = 0; j2 < 4; ++j2)
                    acc[i2][j2] += a[i2] * b[j2];
        }
        __syncthreads();
    }
#pragma unroll
    for (int i2 = 0; i2 < 4; ++i2) {
        const int r = row0 + ty * 4 + i2;
        float4 o;
        o.x = (acc[i2][0] + bias[col0 + tx * 4 + 0]) * scale;
        o.y = (acc[i2][1] + bias[col0 + tx * 4 + 1]) * scale;
        o.z = (acc[i2][2] + bias[col0 + tx * 4 + 2]) * scale;
        o.w = (acc[i2][3] + bias[col0 + tx * 4 + 3]) * scale;
        *reinterpret_cast<float4*>(&C[(size_t)r * N + col0 + tx * 4]) = o;
    }
}

__global__ __launch_bounds__(512) void edge_attn(
    const float* q, const float* __restrict__ kmat, const float* __restrict__ vmat,
    const int* __restrict__ colidx, float* out)
{
    const int i    = blockIdx.x;
    const int h    = threadIdx.x >> 6;
    const int lane = threadIdx.x & 63;
    const size_t base = (size_t)i * EMB + h * HDIM + lane;

    const float qd = q[base];
    int creg = 0;
    if (lane < DEG) creg = colidx[i * DEG + lane];

    float kr[DEG], vr[DEG];
#pragma unroll
    for (int e = 0; e < DEG; ++e) {
        const int ce = __shfl(creg, e, 64);
        const size_t cb = (size_t)ce * EMB + h * HDIM + lane;
        kr[e] = kmat[cb];
        vr[e] = vmat[cb];
    }
    float s[DEG];
#pragma unroll
    for (int e = 0; e < DEG; ++e) {
        float p = qd * kr[e];
#pragma unroll
        for (int off = 32; off; off >>= 1) p += __shfl_xor(p, off, 64);
        s[e] = p;
    }
    float m = s[0];
#pragma unroll
    for (int e = 1; e < DEG; ++e) m = fmaxf(m, s[e]);
    float denom = 0.f;
#pragma unroll
    for (int e = 0; e < DEG; ++e) { s[e] = expf(s[e] - m); denom += s[e]; }
    const float inv = 1.f / denom;
    float o = 0.f;
#pragma unroll
    for (int e = 0; e < DEG; ++e) o += s[e] * vr[e];
    out[base] = o * inv;
}

extern "C" void kernel_launch(void* const* d_in, const int* in_sizes, int n_in,
                              void* d_out, int out_size, void* d_ws, size_t ws_size,
                              hipStream_t stream) {
    const float* query   = (const float*)d_in[0];
    const float* key_    = (const float*)d_in[1];
    const float* value   = (const float*)d_in[2];
    const int*   indices = (const int*)  d_in[3];
    const float* ipw     = (const float*)d_in[4];
    const float* ipb     = (const float*)d_in[5];
    const float* opw     = (const float*)d_in[6];
    const float* opb     = (const float*)d_in[7];
    float* out = (float*)d_out;

    const size_t NEED = 70000000;  // shorts: wqkv+wo+qo+ko+vo+ab = 69.2 MB

    if (ws_size >= NEED) {
        short* wqkv = (short*)d_ws;          // 786432
        short* wo   = wqkv + 786432;         // 262144
        short* qo   = wo + 262144;           // 8388608 each
        short* ko   = qo + 8388608;
        short* vo   = ko + 8388608;
        short* ab   = vo + 8388608;          // attn out bf16

        f2bw<<<512, 256, 0, stream>>>(ipw, wqkv, 98304, opw, wo, 32768);
        gemm_qkv<<<768, 512, 0, stream>>>(query, key_, value, wqkv, ipb,
                                          qo, ko, vo);
        edge_attn5<<<L_NODES / 2, 512, 0, stream>>>(qo, ko, vo,
                                                    indices + NNZ_E, ab);
        gemm_out<<<512, 256, 0, stream>>>(ab, wo, opb, out);
    } else {
        float* qbuf = (float*)d_ws;
        float* kbuf = qbuf + (size_t)L_NODES * EMB;
        float* vbuf = kbuf + (size_t)L_NODES * EMB;
        const dim3 gblk(EMB / TILE, L_NODES / TILE);
        const float scaling = 0.125f;
        gemm_bt<<<gblk, 256, 0, stream>>>(query, ipw,                 ipb,         qbuf,
                                          L_NODES, EMB, EMB, scaling);
        gemm_bt<<<gblk, 256, 0, stream>>>(key_,  ipw + 1 * EMB * EMB, ipb + EMB,   kbuf,
                                          L_NODES, EMB, EMB, 1.f);
        gemm_bt<<<gblk, 256, 0, stream>>>(value, ipw + 2 * EMB * EMB, ipb + 2*EMB, vbuf,
                                          L_NODES, EMB, EMB, 1.f);
        edge_attn<<<L_NODES, 512, 0, stream>>>(qbuf, kbuf, vbuf, indices + NNZ_E, qbuf);
        gemm_bt<<<gblk, 256, 0, stream>>>(qbuf, opw, opb, out, L_NODES, EMB, EMB, 1.f);
    }
}